// Round 22
// baseline (180.013 us; speedup 1.0000x reference)
//
#include <hip/hip_runtime.h>
#include <hip/hip_bf16.h>
#include <cstdint>

// ---------------------------------------------------------------------------
// GABlock, channel-last bf16-MFMA pipeline.
// R22: R20 base + gattn2 grid swapped to (h, gb) so the 4 h-blocks of one gb
//      run adjacently and share qgT cache lines (each 64B line covers 2 h).
// ---------------------------------------------------------------------------

typedef __attribute__((ext_vector_type(8))) short bf8_t;   // 8 bf16 (4 VGPR)
typedef __attribute__((ext_vector_type(4))) float f4_t;    // 4 f32 acc

__device__ __forceinline__ float bf2f(unsigned short u) {
  union { unsigned int i; float f; } x; x.i = ((unsigned int)u) << 16; return x.f;
}
__device__ __forceinline__ unsigned short f2bf(float f) {
  union { float f; unsigned int i; } x; x.f = f;
  unsigned int r = x.i + 0x7FFFu + ((x.i >> 16) & 1u);
  return (unsigned short)(r >> 16);
}
// HW packed f32x2 -> bf16x2 (RNE).
__device__ __forceinline__ unsigned int pk2(float a, float b) {
  unsigned int d;
  asm("v_cvt_pk_bf16_f32 %0, %1, %2" : "=v"(d) : "v"(a), "v"(b));
  return d;
}

#define MB (1048576L)

// ---------------- fused setup: weights->bf16, rpbT, wq2, pos MLP -----------
__global__ void setup_k(
    const float* __restrict__ w0, const float* __restrict__ w1,
    const float* __restrict__ w2, const float* __restrict__ w3,
    const float* __restrict__ w4, const float* __restrict__ w5,
    const float* __restrict__ w6,
    const float* __restrict__ qkv_b, const float* __restrict__ gp_b,
    const float* __restrict__ sw_w, const float* __restrict__ sw_b,
    const float* __restrict__ wn_w, const float* __restrict__ wn_b,
    const float* __restrict__ sw_rpb, const float* __restrict__ wn_rpb,
    const float* __restrict__ pw1, const float* __restrict__ pb1,
    const float* __restrict__ pw2, const float* __restrict__ pb2,
    const float* __restrict__ pw3, const float* __restrict__ pb3,
    unsigned short* __restrict__ wbf, float* __restrict__ biasQG,
    unsigned short* __restrict__ wq2, float* __restrict__ b192,
    float* __restrict__ rpbT_sw, float* __restrict__ rpbT_wn,
    float* __restrict__ ptab) {
  const float QS = 0.35355339059327373f;
  int t = blockIdx.x * 256 + threadIdx.x;
  if (t < 106496) {
    const float* src; int off; float sc = 1.0f;
    if (t < 12288)      { src = w0; off = 0; }
    else if (t < 16384) { src = w1; off = 12288; sc = 0.25f; }
    else if (t < 20480) { src = w2; off = 16384; }
    else if (t < 24576) { src = w3; off = 20480; }
    else if (t < 40960) { src = w4; off = 24576; }
    else if (t < 73728) { src = w5; off = 40960; }
    else                { src = w6; off = 73728; }
    wbf[t] = f2bf(src[t - off] * sc);
  } else if (t < 106752) {
    int i = t - 106496;
    biasQG[i] = i < 192 ? qkv_b[i] : gp_b[i - 192] * 0.25f;
  } else if (t < 119040) {
    int i = t - 106752;
    int row = i >> 6, col = i & 63;
    float v = 0.0f;
    if (row < 96) { if (col < 32) v = sw_w[row * 32 + col]; }
    else          { if (col >= 32) v = wn_w[(row - 96) * 32 + col - 32]; }
    if ((row % 96) < 32) v *= QS;
    wq2[i] = f2bf(v);
  } else if (t < 119232) {
    int i = t - 119040;
    float v = i < 96 ? sw_b[i] : wn_b[i - 96];
    if ((i % 96) < 32) v *= QS;
    b192[i] = v;
  } else if (t < 152000) {
    int i = t - 119232;
    const float* rpb = i < 16384 ? sw_rpb : wn_rpb;
    float* dst = i < 16384 ? rpbT_sw : rpbT_wn;
    int j = i & 16383;
    int h = j >> 12, r = j & 4095, m = r >> 6, n = r & 63;
    int idx = ((n >> 3) - (m >> 3) + 7) * 15 + ((n & 7) - (m & 7) + 7);
    dst[j] = rpb[idx * 4 + h];
  } else if (t < 152961) {
    int j = t - 152000;
    float chv = (float)(j / 31) - 15.0f;
    float cwv = (float)(j % 31) - 15.0f;
    float t1[16], t2[16];
#pragma unroll
    for (int i = 0; i < 16; ++i) {
      float s = fmaf(pw1[i * 2], chv, fmaf(pw1[i * 2 + 1], cwv, pb1[i]));
      t1[i] = fmaxf(s, 0.0f);
    }
#pragma unroll
    for (int i = 0; i < 16; ++i) {
      float s = pb2[i];
#pragma unroll
      for (int k = 0; k < 16; ++k) s = fmaf(pw2[i * 16 + k], t1[k], s);
      t2[i] = fmaxf(s, 0.0f);
    }
#pragma unroll
    for (int hh = 0; hh < 4; ++hh) {
      float s = pb3[hh];
#pragma unroll
      for (int k = 0; k < 16; ++k) s = fmaf(pw3[hh * 16 + k], t2[k], s);
      ptab[j * 4 + hh] = s;
    }
  }
}

// A21 = A2 @ A1 (64x64, fp32 accum -> bf16 into wbf a2 slot); b21 = A2@a1_b + a2_b
__global__ void wfold_k(const float* __restrict__ a1w, const float* __restrict__ a1b,
                        const float* __restrict__ a2w, const float* __restrict__ a2b,
                        unsigned short* __restrict__ w21, float* __restrict__ b21) {
  int t = blockIdx.x * 256 + threadIdx.x;   // 4096
  int co = t >> 6, ci = t & 63;
  float s = 0.0f;
#pragma unroll 8
  for (int k = 0; k < 64; ++k) s = fmaf(a2w[co * 64 + k], a1w[k * 64 + ci], s);
  w21[t] = f2bf(s);
  if (t < 64) {
    float b = a2b[t];
#pragma unroll 8
    for (int k = 0; k < 64; ++k) b = fmaf(a2w[t * 64 + k], a1b[k], b);
    b21[t] = b;
  }
}

// pbTh[h][m][q] bf16
__global__ void pbT_k(const float* __restrict__ table, unsigned short* __restrict__ pbTh) {
  int t = blockIdx.x * 256 + threadIdx.x;   // 262144
  int hh = t >> 16;
  int r = t & 65535;
  int m = r >> 8;
  int q = r & 255;
  int idx = ((q >> 4) - (m >> 4) + 15) * 31 + ((q & 15) - (m & 15) + 15);
  pbTh[t] = f2bf(table[idx * 4 + hh]);
}

// ---------------- NCHW fp32 -> channel-last bf16 ---------------------------
__global__ __launch_bounds__(256) void tin_k(const float* __restrict__ x,
                                             unsigned short* __restrict__ xTb) {
  __shared__ float tile[64][132];
  const int b = blockIdx.z, px0 = blockIdx.x * 64, tid = threadIdx.x;
#pragma unroll
  for (int i = 0; i < 8; ++i) {
    int e = i * 256 + tid;
    int c = e >> 4, p4 = (e & 15) * 4;
    float4 v = *(const float4*)(x + (((size_t)(b * 128 + c)) << 14) + px0 + p4);
    tile[p4][c] = v.x; tile[p4 + 1][c] = v.y; tile[p4 + 2][c] = v.z; tile[p4 + 3][c] = v.w;
  }
  __syncthreads();
#pragma unroll
  for (int i = 0; i < 8; ++i) {
    int e = i * 256 + tid;
    int px = e >> 5, c4 = (e & 31) * 4;
    uint2 w = {pk2(tile[px][c4], tile[px][c4 + 1]), pk2(tile[px][c4 + 2], tile[px][c4 + 3])};
    *(uint2*)(xTb + ((size_t)(b * 16384 + px0 + px)) * 128 + c4) = w;
  }
}

// ---------------- generic bf16-MFMA GEMM -----------------------------------
// EPI: 0 plain->bf16, 1 gelu->bf16, 2 cLN+res(bf16)->bf16,
//      3 cLN+res(bf16)+res2(bf16)->f32 NCHW full-line stores
template <int NF, int KC, int EPI, int OSHUF>
__global__ __launch_bounds__(256) void gemm_k(
    const unsigned short* __restrict__ A, int a_rs, int a_c0,
    const unsigned short* __restrict__ W, const float* __restrict__ bias,
    const float* __restrict__ g, const float* __restrict__ bb,
    const unsigned short* __restrict__ resf, const unsigned short* __restrict__ resb,
    void* __restrict__ out, int o_rs, int o_c0) {
  __shared__ __align__(16) char Asw[128 * 128];
  __shared__ __align__(16) char Bsw[NF * 16 * 128];
  const int tid = threadIdx.x;
  const int lane = tid & 63, wv = tid >> 6, wpx = wv * 32;
  const int lr = lane & 15, lg = lane >> 4;
  const int px0 = blockIdx.x * 128;
  const int co0 = blockIdx.y * (NF * 16);

  f4_t acc[2][NF];
#pragma unroll
  for (int mf = 0; mf < 2; ++mf)
#pragma unroll
    for (int nf = 0; nf < NF; ++nf) acc[mf][nf] = (f4_t){0.f, 0.f, 0.f, 0.f};

  for (int kc = 0; kc < KC; ++kc) {
    const int k0 = kc * 64;
    if (kc) __syncthreads();
#pragma unroll
    for (int i = 0; i < 4; ++i) {
      int e = i * 256 + tid;
      int row = e >> 3, q8 = e & 7;
      const unsigned short* src = A + (size_t)(px0 + row) * a_rs + a_c0 + k0 + q8 * 8;
      *(uint4*)(Asw + row * 128 + ((q8 ^ (row & 7)) << 4)) = *(const uint4*)src;
    }
#pragma unroll
    for (int i = 0; i < NF / 2; ++i) {
      int e = i * 256 + tid;
      int row = e >> 3, q8 = e & 7;
      const unsigned short* src = W + (size_t)(co0 + row) * (KC * 64) + k0 + q8 * 8;
      *(uint4*)(Bsw + row * 128 + ((q8 ^ (row & 7)) << 4)) = *(const uint4*)src;
    }
    __syncthreads();
#pragma unroll
    for (int ks = 0; ks < 2; ++ks) {
      const int xk = (((ks * 4) + lg) ^ (lane & 7)) << 4;
      bf8_t av[2], bv[NF];
#pragma unroll
      for (int mf = 0; mf < 2; ++mf)
        av[mf] = *(const bf8_t*)(Asw + (wpx + mf * 16 + lr) * 128 + xk);
#pragma unroll
      for (int nf = 0; nf < NF; ++nf)
        bv[nf] = *(const bf8_t*)(Bsw + (nf * 16 + lr) * 128 + xk);
#pragma unroll
      for (int mf = 0; mf < 2; ++mf)
#pragma unroll
        for (int nf = 0; nf < NF; ++nf)
          acc[mf][nf] = __builtin_amdgcn_mfma_f32_16x16x32_bf16(av[mf], bv[nf], acc[mf][nf], 0, 0, 0);
    }
  }

  float bco[NF];
#pragma unroll
  for (int nf = 0; nf < NF; ++nf) bco[nf] = bias[co0 + nf * 16 + lr];

  if constexpr (EPI >= 2) {
    float gv[NF], bbv[NF];
#pragma unroll
    for (int nf = 0; nf < NF; ++nf) { gv[nf] = g[nf * 16 + lr]; bbv[nf] = bb[nf * 16 + lr]; }
#pragma unroll
    for (int mf = 0; mf < 2; ++mf)
#pragma unroll
      for (int nf = 0; nf < NF; ++nf)
#pragma unroll
        for (int r = 0; r < 4; ++r) acc[mf][nf][r] += bco[nf];
#pragma unroll
    for (int mf = 0; mf < 2; ++mf) {
      float mus[4], rss[4];
#pragma unroll
      for (int r = 0; r < 4; ++r) {
        float s = 0.f, q = 0.f;
#pragma unroll
        for (int nf = 0; nf < NF; ++nf) {
          float v = acc[mf][nf][r];
          s += v; q += v * v;
        }
#pragma unroll
        for (int msk = 1; msk < 16; msk <<= 1) {
          s += __shfl_xor(s, msk);
          q += __shfl_xor(q, msk);
        }
        float mu = s * (1.0f / 128.0f);
        float var = q * (1.0f / 128.0f) - mu * mu;
        mus[r] = mu;
        rss[r] = rsqrtf(var + 1e-5f);
      }
      if constexpr (EPI == 2) {
#pragma unroll
        for (int r = 0; r < 4; ++r) {
          int px_e = px0 + wpx + mf * 16 + lg * 4 + r;
          const unsigned short* xr = resf + (size_t)px_e * 128 + lr;
          unsigned short* op = (unsigned short*)out + (size_t)px_e * o_rs + lr;
#pragma unroll
          for (int nf = 0; nf < NF; ++nf) {
            float v = (acc[mf][nf][r] - mus[r]) * rss[r] * gv[nf] + bbv[nf] + bf2f(xr[nf * 16]);
            op[nf * 16] = f2bf(v);
          }
        }
      } else {  // EPI == 3: fp32 NCHW, one float4 (4 px) per channel per thread
        int pxb = px0 + wpx + mf * 16 + lg * 4;
        int b_ = pxb >> 14, p_ = pxb & 16383;
#pragma unroll
        for (int nf = 0; nf < NF; ++nf) {
          int ch = lr + nf * 16;
          float vr[4];
#pragma unroll
          for (int r = 0; r < 4; ++r) {
            float xv  = bf2f(resf[(size_t)(pxb + r) * 128 + ch]);
            float x2v = bf2f(resb[(size_t)(pxb + r) * 128 + ch]);
            vr[r] = (acc[mf][nf][r] - mus[r]) * rss[r] * gv[nf] + bbv[nf] + xv + x2v;
          }
          float4 v4 = {vr[0], vr[1], vr[2], vr[3]};
          *(float4*)((float*)out + (((size_t)(b_ * 128 + ch)) << 14) + p_) = v4;
        }
      }
    }
  } else {
#pragma unroll
    for (int mf = 0; mf < 2; ++mf) {
#pragma unroll
      for (int r = 0; r < 4; ++r) {
        int px_e = px0 + wpx + mf * 16 + lg * 4 + r;
        size_t orow;
        int cadj = co0;
        if constexpr (OSHUF == 0) {
          orow = (size_t)px_e;
        } else if constexpr (OSHUF == 1) {
          int b = px_e >> 14, p = px_e & 16383, hh = p >> 7, w_ = p & 127;
          orow = (size_t)(b * 64 + (hh & 7) * 8 + (w_ & 7)) * 256 + ((hh >> 3) * 16 + (w_ >> 3));
        } else if constexpr (OSHUF == 2) {
          int gbb = px_e >> 8, n = px_e & 255;
          int b = gbb >> 6, ih = (gbb >> 3) & 7, iw = gbb & 7;
          orow = (size_t)b * 16384 + ((n >> 4) * 8 + ih) * 128 + (n & 15) * 8 + iw;
        } else {  // window-order: br0 = sw(shift 4), br1 = wn(shift 0)
          int brx = (co0 >= 96);
          int b = px_e >> 14, p = px_e & 16383, hh = p >> 7, w_ = p & 127;
          int sh = brx ? 0 : 4;
          int h2 = (hh - sh) & 127, w2_ = (w_ - sh) & 127;
          orow = (size_t)brx * 65536 + (size_t)b * 16384 +
                 (size_t)(((h2 >> 3) * 16 + (w2_ >> 3)) * 64 + (h2 & 7) * 8 + (w2_ & 7));
          cadj = co0 - brx * 96;
        }
        unsigned short* op = (unsigned short*)out + orow * o_rs + o_c0 + cadj + lr;
#pragma unroll
        for (int nf = 0; nf < NF; ++nf) {
          float v = acc[mf][nf][r] + bco[nf];
          if constexpr (EPI == 1) v = 0.5f * v * (1.0f + erff(v * 0.7071067811865475f));
          op[nf * 16] = f2bf(v);
        }
      }
    }
  }
}

// ---------------- fused double grid attention (8 waves x 32 queries) -------
// Block = (h, gb) [h fast so same-gb blocks share qgT cache lines].
// Phase 1: O1 = softmax(G K^T + B) V -> LDS. Phase 2: O2 = softmax(q G^T + B) O1.
__global__ __launch_bounds__(512, 4) void gattn2_k(
    const unsigned short* __restrict__ qgT,
    const unsigned short* __restrict__ pbTh, unsigned short* __restrict__ outb) {
  __shared__ __align__(16) unsigned short K_lds[256 * 16];   // 8 KB  [m][16d]
  __shared__ __align__(16) unsigned short G_lds[256 * 16];   // 8 KB  [m][16d]
  __shared__ __align__(16) unsigned short Vt[16 * 256];      // 8 KB  swz [d][m]
  __shared__ __align__(16) unsigned short Vt2[16 * 256];     // 8 KB  swz [d][m] (O1)
  __shared__ __align__(16) unsigned short P_lds[8 * 32 * 32];// 16 KB per-wave swz
  const int h = blockIdx.x, gb = blockIdx.y, tid = threadIdx.x;
  const int lane = tid & 63, wv = tid >> 6;        // wv in [0,8)
  const int lr = lane & 15, lg = lane >> 4;
  const int q0 = wv * 32;
  const f4_t z4 = {0.f, 0.f, 0.f, 0.f};
  const bf8_t bz = {0, 0, 0, 0, 0, 0, 0, 0};
  unsigned short* Pw = &P_lds[wv * 32 * 32];
  const unsigned short* bpm_base = pbTh + ((size_t)(h * 256) << 8);

  // ---- stage K rows + G rows (threads 0-255) and V^T (threads 256-511) ----
  if (tid < 256) {
    const unsigned short* kp = qgT + (size_t)(gb * 256 + tid) * 256 + 64 + h * 16;
    *(uint4*)&K_lds[tid * 16]     = *(const uint4*)kp;
    *(uint4*)&K_lds[tid * 16 + 8] = *(const uint4*)(kp + 8);
    const unsigned short* gp = qgT + (size_t)(gb * 256 + tid) * 256 + 192 + h * 16;
    *(uint4*)&G_lds[tid * 16]     = *(const uint4*)gp;
    *(uint4*)&G_lds[tid * 16 + 8] = *(const uint4*)(gp + 8);
  } else {
    int m = tid - 256;
    const unsigned short* vp = qgT + (size_t)(gb * 256 + m) * 256 + 128 + h * 16;
    uint4 va = *(const uint4*)vp;
    uint4 vb = *(const uint4*)(vp + 8);
    unsigned int w8[8] = {va.x, va.y, va.z, va.w, vb.x, vb.y, vb.z, vb.w};
    int chb = m >> 3, wi = m & 7;
#pragma unroll
    for (int w = 0; w < 8; ++w) {
      int d0 = 2 * w, d1 = 2 * w + 1;
      Vt[d0 * 256 + ((chb ^ (d0 & 7)) << 3) + wi] = (unsigned short)(w8[w] & 0xffff);
      Vt[d1 * 256 + ((chb ^ (d1 & 7)) << 3) + wi] = (unsigned short)(w8[w] >> 16);
    }
  }
  __syncthreads();

  // ================= phase 1: O1 = softmax(G K^T + B) V =================
  {
    bf8_t bq[2];
#pragma unroll
    for (int qt = 0; qt < 2; ++qt) {
      bq[qt] = bz;
      if (lg < 2)
        bq[qt] = *(const bf8_t*)&G_lds[(q0 + qt * 16 + lr) * 16 + lg * 8];
    }
    f4_t oacc[2];
    float lrun[2];
#pragma unroll
    for (int qt = 0; qt < 2; ++qt) { oacc[qt] = z4; lrun[qt] = 0.0f; }

    for (int m0 = 0; m0 < 256; m0 += 32) {
      bf8_t ak0 = bz, ak1 = bz;
      if (lg < 2) {
        ak0 = *(const bf8_t*)&K_lds[(m0 + lr) * 16 + lg * 8];
        ak1 = *(const bf8_t*)&K_lds[(m0 + 16 + lr) * 16 + lg * 8];
      }
      bf8_t av = *(const bf8_t*)&Vt[lr * 256 + ((((m0 >> 3) + lg) ^ (lr & 7)) << 3)];

#pragma unroll
      for (int qt = 0; qt < 2; ++qt) {
        const unsigned short* bpm = bpm_base + ((size_t)(m0 + lg * 4) << 8) + q0 + qt * 16 + lr;
        f4_t c0v = {bf2f(bpm[0]), bf2f(bpm[256]), bf2f(bpm[512]), bf2f(bpm[768])};
        f4_t c1v = {bf2f(bpm[4096]), bf2f(bpm[4352]), bf2f(bpm[4608]), bf2f(bpm[4864])};
        f4_t st0 = __builtin_amdgcn_mfma_f32_16x16x32_bf16(ak0, bq[qt], c0v, 0, 0, 0);
        f4_t st1 = __builtin_amdgcn_mfma_f32_16x16x32_bf16(ak1, bq[qt], c1v, 0, 0, 0);
        float p0[4], p1[4], ls = 0.0f;
#pragma unroll
        for (int r = 0; r < 4; ++r) {
          p0[r] = __expf(st0[r]);
          p1[r] = __expf(st1[r]);
          ls += p0[r] + p1[r];
        }
        ls += __shfl_xor(ls, 16);
        ls += __shfl_xor(ls, 32);
        lrun[qt] += ls;
        int row = qt * 16 + lr;
        int rw3 = row & 3;
        uint2 w0 = {pk2(p0[0], p0[1]), pk2(p0[2], p0[3])};
        uint2 w1 = {pk2(p1[0], p1[1]), pk2(p1[2], p1[3])};
        *(uint2*)&Pw[row * 32 + ((((lg >> 1)) ^ rw3) << 3) + (lg & 1) * 4]     = w0;
        *(uint2*)&Pw[row * 32 + (((2 + (lg >> 1)) ^ rw3) << 3) + (lg & 1) * 4] = w1;
      }
#pragma unroll
      for (int qt = 0; qt < 2; ++qt) {
        int row = qt * 16 + lr;
        bf8_t bp = *(const bf8_t*)&Pw[row * 32 + ((lg ^ (row & 3)) << 3)];
        oacc[qt] = __builtin_amdgcn_mfma_f32_16x16x32_bf16(av, bp, oacc[qt], 0, 0, 0);
      }
    }
    // O1 -> Vt2 (swizzled [d][m]): lane holds O^T[d = lg*4+r][m = q0+qt*16+lr]
#pragma unroll
    for (int qt = 0; qt < 2; ++qt) {
      float inv = 1.0f / lrun[qt];
      int m = q0 + qt * 16 + lr;
      int chb = m >> 3, wi = m & 7;
      unsigned int pA = pk2(oacc[qt][0] * inv, oacc[qt][1] * inv);
      unsigned int pB = pk2(oacc[qt][2] * inv, oacc[qt][3] * inv);
      int d0 = lg * 4;
      Vt2[(d0    ) * 256 + ((chb ^ ((d0    ) & 7)) << 3) + wi] = (unsigned short)(pA & 0xffff);
      Vt2[(d0 + 1) * 256 + ((chb ^ ((d0 + 1) & 7)) << 3) + wi] = (unsigned short)(pA >> 16);
      Vt2[(d0 + 2) * 256 + ((chb ^ ((d0 + 2) & 7)) << 3) + wi] = (unsigned short)(pB & 0xffff);
      Vt2[(d0 + 3) * 256 + ((chb ^ ((d0 + 3) & 7)) << 3) + wi] = (unsigned short)(pB >> 16);
    }
  }
  __syncthreads();

  // ================= phase 2: O2 = softmax(q G^T + B) O1 =================
  {
    bf8_t bq[2];
#pragma unroll
    for (int qt = 0; qt < 2; ++qt) {
      bq[qt] = bz;
      if (lg < 2)
        bq[qt] = *(const bf8_t*)(qgT + (size_t)(gb * 256 + q0 + qt * 16 + lr) * 256 + h * 16 + lg * 8);
    }
    f4_t oacc[2];
    float lrun[2];
#pragma unroll
    for (int qt = 0; qt < 2; ++qt) { oacc[qt] = z4; lrun[qt] = 0.0f; }

    for (int m0 = 0; m0 < 256; m0 += 32) {
      bf8_t ak0 = bz, ak1 = bz;
      if (lg < 2) {
        ak0 = *(const bf8_t*)&G_lds[(m0 + lr) * 16 + lg * 8];
        ak1 = *(const bf8_t*)&G_lds[(m0 + 16 + lr) * 16 + lg * 8];
      }
      bf8_t av = *(const bf8_t*)&Vt2[lr * 256 + ((((m0 >> 3) + lg) ^ (lr & 7)) << 3)];

#pragma unroll
      for (int qt = 0; qt < 2; ++qt) {
        const unsigned short* bpm = bpm_base + ((size_t)(m0 + lg * 4) << 8) + q0 + qt * 16 + lr;
        f4_t c0v = {bf2f(bpm[0]), bf2f(bpm[256]), bf2f(bpm[512]), bf2f(bpm[768])};
        f4_t c1v = {bf2f(bpm[4096]), bf2f(bpm[4352]), bf2f(bpm[4608]), bf2f(bpm[4864])};
        f4_t st0 = __builtin_amdgcn_mfma_f32_16x16x32_bf16(ak0, bq[qt], c0v, 0, 0, 0);
        f4_t st1 = __builtin_amdgcn_mfma_f32_16x16x32_bf16(ak1, bq[qt], c1v, 0, 0, 0);
        float p0[4], p1[4], ls = 0.0f;
#pragma unroll
        for (int r = 0; r < 4; ++r) {
          p0[r] = __expf(st0[r]);
          p1[r] = __expf(st1[r]);
          ls += p0[r] + p1[r];
        }
        ls += __shfl_xor(ls, 16);
        ls += __shfl_xor(ls, 32);
        lrun[qt] += ls;
        int row = qt * 16 + lr;
        int rw3 = row & 3;
        uint2 w0 = {pk2(p0[0], p0[1]), pk2(p0[2], p0[3])};
        uint2 w1 = {pk2(p1[0], p1[1]), pk2(p1[2], p1[3])};
        *(uint2*)&Pw[row * 32 + ((((lg >> 1)) ^ rw3) << 3) + (lg & 1) * 4]     = w0;
        *(uint2*)&Pw[row * 32 + (((2 + (lg >> 1)) ^ rw3) << 3) + (lg & 1) * 4] = w1;
      }
#pragma unroll
      for (int qt = 0; qt < 2; ++qt) {
        int row = qt * 16 + lr;
        bf8_t bp = *(const bf8_t*)&Pw[row * 32 + ((lg ^ (row & 3)) << 3)];
        oacc[qt] = __builtin_amdgcn_mfma_f32_16x16x32_bf16(av, bp, oacc[qt], 0, 0, 0);
      }
    }
#pragma unroll
    for (int qt = 0; qt < 2; ++qt) {
      float inv = 1.0f / lrun[qt];
      uint2 o;
      o.x = pk2(oacc[qt][0] * inv, oacc[qt][1] * inv);
      o.y = pk2(oacc[qt][2] * inv, oacc[qt][3] * inv);
      unsigned short* op = outb + (size_t)(gb * 256 + q0 + qt * 16 + lr) * 64 + h * 16 + lg * 4;
      *(uint2*)op = o;
    }
  }
}

// ---------------- MFMA swin window attention (barrier-free) ----------------
__global__ __launch_bounds__(256) void swat_k(
    const unsigned short* __restrict__ qkv2,
    const float* __restrict__ rpbT_sw, const float* __restrict__ rpbT_wn,
    const float* __restrict__ sw_pw, const float* __restrict__ sw_pb,
    const float* __restrict__ wn_pw, const float* __restrict__ wn_pb,
    unsigned short* __restrict__ yT) {
  __shared__ __align__(16) unsigned short Vt[4 * 8 * 64];
  __shared__ __align__(16) unsigned short Pt[4 * 64 * 64];
  __shared__ __align__(16) unsigned short aoT[4 * 64 * 32];
  const int tid = threadIdx.x, lane = tid & 63, wv = tid >> 6;
  const int lr = lane & 15, lg = lane >> 4;
  const int br = blockIdx.y;
  const int win = blockIdx.x * 4 + wv;
  const int b = win >> 8, wl = win & 255, wh = wl >> 4, ww = wl & 15;
  const float* rpbT = br ? rpbT_wn : rpbT_sw;
  const float* pw   = br ? wn_pw : sw_pw;
  const float* pb   = br ? wn_pb : sw_pb;
  const int shift = br ? 0 : 4;
  const int yc0 = br ? 0 : 32;
  const bool edge = (shift > 0) && (wh == 15 || ww == 15);

  const unsigned short* qw = qkv2 + (size_t)br * 65536 * 96 + (size_t)win * 64 * 96;
  const f4_t z4 = {0.f, 0.f, 0.f, 0.f};
  const bf8_t bz = {0, 0, 0, 0, 0, 0, 0, 0};
  unsigned short* Vw = &Vt[wv * 8 * 64];
  unsigned short* Pw = &Pt[wv * 64 * 64];
  unsigned short* aw_ = &aoT[wv * 64 * 32];

#pragma unroll 1
  for (int h = 0; h < 4; ++h) {
    {
      uint4 v = *(const uint4*)(qw + lane * 96 + 64 + h * 8);
      unsigned int w4[4] = {v.x, v.y, v.z, v.w};
      int chb = lane >> 3, wi = lane & 7;
#pragma unroll
      for (int j = 0; j < 4; ++j) {
        int d0 = 2 * j, d1 = 2 * j + 1;
        Vw[d0 * 64 + ((chb ^ (d0 & 7)) << 3) + wi] = (unsigned short)(w4[j] & 0xffff);
        Vw[d1 * 64 + ((chb ^ (d1 & 7)) << 3) + wi] = (unsigned short)(w4[j] >> 16);
      }
    }
    bf8_t bq[4];
#pragma unroll
    for (int nt = 0; nt < 4; ++nt) {
      bq[nt] = bz;
      if (lg == 0) bq[nt] = *(const bf8_t*)(qw + (nt * 16 + lr) * 96 + h * 8);
    }
    f4_t st[4][4];
#pragma unroll
    for (int mt = 0; mt < 4; ++mt) {
      bf8_t ak = bz;
      if (lg == 0) ak = *(const bf8_t*)(qw + (mt * 16 + lr) * 96 + 32 + h * 8);
#pragma unroll
      for (int nt = 0; nt < 4; ++nt) {
        const float* rp = rpbT + h * 4096 + (mt * 16 + lg * 4) * 64 + nt * 16 + lr;
        f4_t cb = {rp[0], rp[64], rp[128], rp[192]};
        st[mt][nt] = __builtin_amdgcn_mfma_f32_16x16x32_bf16(ak, bq[nt], cb, 0, 0, 0);
      }
    }
#pragma unroll
    for (int nt = 0; nt < 4; ++nt) {
      float sv[16];
#pragma unroll
      for (int mt = 0; mt < 4; ++mt)
#pragma unroll
        for (int r = 0; r < 4; ++r) sv[mt * 4 + r] = st[mt][nt][r];
      if (edge) {
        int n = nt * 16 + lr;
        int regn = ((wh < 15) ? 0 : (((n >> 3) < 4) ? 1 : 2)) * 3 +
                   ((ww < 15) ? 0 : (((n & 7) < 4) ? 1 : 2));
#pragma unroll
        for (int mt = 0; mt < 4; ++mt)
#pragma unroll
          for (int r = 0; r < 4; ++r) {
            int m = mt * 16 + lg * 4 + r;
            int regm = ((wh < 15) ? 0 : (((m >> 3) < 4) ? 1 : 2)) * 3 +
                       ((ww < 15) ? 0 : (((m & 7) < 4) ? 1 : 2));
            if (regm != regn) sv[mt * 4 + r] -= 100.0f;
          }
      }
      float l = 0.0f;
#pragma unroll
      for (int i = 0; i < 16; ++i) {
        sv[i] = __expf(sv[i]);
        l += sv[i];
      }
      l += __shfl_xor(l, 16);
      l += __shfl_xor(l, 32);
      float inv = 1.0f / l;
      int row = nt * 16 + lr, rw7 = lr & 7;
#pragma unroll
      for (int mt = 0; mt < 4; ++mt) {
        uint2 w = {pk2(sv[mt * 4] * inv, sv[mt * 4 + 1] * inv),
                   pk2(sv[mt * 4 + 2] * inv, sv[mt * 4 + 3] * inv)};
        *(uint2*)&Pw[row * 64 + (((2 * mt + (lg >> 1)) ^ rw7) << 3) + (lg & 1) * 4] = w;
      }
    }
    f4_t oa[4] = {z4, z4, z4, z4};
#pragma unroll
    for (int ks = 0; ks < 2; ++ks) {
      bf8_t av = bz;
      if (lr < 8) av = *(const bf8_t*)&Vw[lr * 64 + (((4 * ks + lg) ^ (lr & 7)) << 3)];
#pragma unroll
      for (int nt = 0; nt < 4; ++nt) {
        int row = nt * 16 + lr;
        bf8_t bp = *(const bf8_t*)&Pw[row * 64 + (((4 * ks + lg) ^ (lr & 7)) << 3)];
        oa[nt] = __builtin_amdgcn_mfma_f32_16x16x32_bf16(av, bp, oa[nt], 0, 0, 0);
      }
    }
    if (lg < 2) {
#pragma unroll
      for (int nt = 0; nt < 4; ++nt) {
        uint2 w = {pk2(oa[nt][0], oa[nt][1]), pk2(oa[nt][2], oa[nt][3])};
        int row = nt * 16 + lr;
        *(uint2*)&aw_[row * 32 + ((h ^ (lr & 3)) << 3) + lg * 4] = w;
      }
    }
  }

#pragma unroll
  for (int mt = 0; mt < 2; ++mt) {
    const float* wr = pw + (mt * 16 + lr) * 32 + lg * 8;
    float4 a0 = *(const float4*)wr, a1 = *(const float4*)(wr + 4);
    union { uint4 u; bf8_t v; } aw;
    aw.u.x = pk2(a0.x, a0.y); aw.u.y = pk2(a0.z, a0.w);
    aw.u.z = pk2(a1.x, a1.y); aw.u.w = pk2(a1.z, a1.w);
    float pb0 = pb[mt * 16 + lg * 4], pb1 = pb[mt * 16 + lg * 4 + 1];
    float pb2 = pb[mt * 16 + lg * 4 + 2], pb3 = pb[mt * 16 + lg * 4 + 3];
#pragma unroll
    for (int nt = 0; nt < 4; ++nt) {
      int row = nt * 16 + lr;
      bf8_t bo = *(const bf8_t*)&aw_[row * 32 + ((lg ^ (lr & 3)) << 3)];
      f4_t po = __builtin_amdgcn_mfma_f32_16x16x32_bf16(aw.v, bo, z4, 0, 0, 0);
      int n = nt * 16 + lr;
      int hdst = (wh * 8 + (n >> 3) + shift) & 127;
      int wdst = (ww * 8 + (n & 7) + shift) & 127;
      uint2 w = {pk2(po[0] + pb0, po[1] + pb1), pk2(po[2] + pb2, po[3] + pb3)};
      *(uint2*)(yT + ((size_t)(b * 16384 + hdst * 128 + wdst)) * 128 + yc0 + mt * 16 + lg * 4) = w;
    }
  }
}

// ---------------------------------------------------------------------------
extern "C" void kernel_launch(void* const* d_in, const int* in_sizes, int n_in,
                              void* d_out, int out_size, void* d_ws, size_t ws_size,
                              hipStream_t stream) {
  (void)in_sizes; (void)n_in; (void)out_size; (void)ws_size;
  const float* x        = (const float*)d_in[0];
  const float* ln_g     = (const float*)d_in[1];
  const float* ln_b     = (const float*)d_in[2];
  const float* ga_qkv_w = (const float*)d_in[3];
  const float* ga_qkv_b = (const float*)d_in[4];
  const float* ga_gp_w  = (const float*)d_in[5];
  const float* ga_gp_b  = (const float*)d_in[6];
  const float* pos_w1   = (const float*)d_in[7];
  const float* pos_b1   = (const float*)d_in[8];
  const float* pos_w2   = (const float*)d_in[9];
  const float* pos_b2   = (const float*)d_in[10];
  const float* pos_w3   = (const float*)d_in[11];
  const float* pos_b3   = (const float*)d_in[12];
  const float* a1_pw    = (const float*)d_in[13];
  const float* a1_pb    = (const float*)d_in[14];
  const float* a2_pw    = (const float*)d_in[15];
  const float* a2_pb    = (const float*)d_in[16];
  const float* sw_qkv_w = (const float*)d_in[17];
  const float* sw_qkv_b = (const float*)d_in[18];
  const float* sw_rpb   = (const float*)d_in[19];
  const float* sw_pw    = (const float*)d_in[20];
  const float* sw_pb    = (const float*)d_in[21];
  const float* wn_qkv_w = (const float*)d_in[22];
  const float* wn_qkv_b = (const float*)d_in[23];
  const float* wn_rpb   = (const float*)d_in[24];
  const float* wn_pw    = (const float*)d_in[25];
  const float* wn_pb    = (const float*)d_in[26];
  const float* fc_w     = (const float*)d_in[27];
  const float* fc_b     = (const float*)d_in[28];
  const float* n2_g     = (const float*)d_in[29];
  const float* n2_b     = (const float*)d_in[30];
  const float* m1_w     = (const float*)d_in[31];
  const float* m1_b     = (const float*)d_in[32];
  const float* m2_w     = (const float*)d_in[33];
  const float* m2_b     = (const float*)d_in[34];
  float* out = (float*)d_out;
  char* base = (char*)d_ws;

  unsigned short* xTb    = (unsigned short*)(base);           // 16 MB
  unsigned short* qgT    = (unsigned short*)(base + 16 * MB); // 32 MB [px][256: q|k|v|g]
  unsigned short* t2T    = (unsigned short*)(base + 48 * MB); //  8 MB
  unsigned short* yT     = (unsigned short*)(base + 64 * MB); // 16 MB
  unsigned short* x2T    = (unsigned short*)(base + 80 * MB); // 16 MB
  unsigned short* qkv2   = (unsigned short*)(base + 16 * MB); // 24 MB alias (after gattn)
  unsigned short* hT     = (unsigned short*)(base + 16 * MB); // 32 MB alias (after swat)
  unsigned short* pbTh   = (unsigned short*)(base + 96 * MB); // 512 KB bf16 [h][m][q]
  float*          ptab   = (float*)(base + 97 * MB);          // 16 KB
  float*          rpbT_sw= (float*)(base + 97 * MB + 65536);  // 64 KB f32
  float*          rpbT_wn= (float*)(base + 97 * MB + 131072); // 64 KB f32
  unsigned short* wq2bf  = (unsigned short*)(base + 97 * MB + 196608); // 24 KB
  float*          bias192= (float*)(base + 97 * MB + 229376);          // 768 B
  float*          biasQG = (float*)(base + 97 * MB + 230400);          // 1 KB
  float*          b21    = (float*)(base + 97 * MB + 231424);          // 256 B
  unsigned short* wbf    = (unsigned short*)(base + 97 * MB + 262144); // 208 KB

  setup_k<<<598, 256, 0, stream>>>(
      ga_qkv_w, ga_gp_w, a1_pw, a2_pw, fc_w, m1_w, m2_w,
      ga_qkv_b, ga_gp_b,
      sw_qkv_w, sw_qkv_b, wn_qkv_w, wn_qkv_b,
      sw_rpb, wn_rpb,
      pos_w1, pos_b1, pos_w2, pos_b2, pos_w3, pos_b3,
      wbf, biasQG, wq2bf, bias192, rpbT_sw, rpbT_wn, ptab);
  wfold_k<<<16, 256, 0, stream>>>(a1_pw, a1_pb, a2_pw, a2_pb, wbf + 20480, b21);
  pbT_k<<<1024, 256, 0, stream>>>(ptab, pbTh);

  tin_k<<<dim3(256, 1, 4), 256, 0, stream>>>(x, xTb);

  // grid branch: one merged qkv+gp GEMM (256 out-ch, NF=8), grid-shuffled
  gemm_k<8, 1, 0, 1><<<dim3(512, 2, 1), 256, 0, stream>>>(
      xTb, 128, 0, wbf, biasQG, nullptr, nullptr, nullptr, nullptr, qgT, 256, 0);

  // fused attn1+attn2 -> t2   (grid = (h, gb): h fast for qgT line sharing)
  gattn2_k<<<dim3(4, 256), 512, 0, stream>>>(qgT, pbTh, t2T);

  // folded a2 (A2@A1) + unshuffle -> yT[64:128]
  gemm_k<4, 1, 0, 2><<<dim3(512, 1, 1), 256, 0, stream>>>(
      t2T, 64, 0, wbf + 20480, b21, nullptr, nullptr, nullptr, nullptr, yT, 128, 64);

  // window branches: qkv GEMM (window-ordered) + MFMA attention
  gemm_k<6, 1, 0, 3><<<dim3(512, 2, 1), 256, 0, stream>>>(
      xTb, 128, 64, wq2bf, bias192, nullptr, nullptr, nullptr, nullptr, qkv2, 96, 0);
  swat_k<<<dim3(256, 2), 256, 0, stream>>>(
      qkv2, rpbT_sw, rpbT_wn, sw_pw, sw_pb, wn_pw, wn_pb, yT);

  // fc + cLN + residual(x bf16) -> x2T
  gemm_k<8, 2, 2, 0><<<dim3(512, 1, 1), 256, 0, stream>>>(
      yT, 128, 0, wbf + 24576, fc_b, ln_g, ln_b, xTb, nullptr, x2T, 128, 0);

  // MLP: m1 (gelu) -> hT ; m2 + cLN + x2 + shortcut -> out (fp32 NCHW)
  gemm_k<8, 2, 1, 0><<<dim3(512, 2, 1), 256, 0, stream>>>(
      x2T, 128, 0, wbf + 40960, m1_b, nullptr, nullptr, nullptr, nullptr, hT, 256, 0);
  gemm_k<8, 4, 3, 0><<<dim3(512, 1, 1), 256, 0, stream>>>(
      hT, 256, 0, wbf + 73728, m2_b, n2_g, n2_b, xTb, x2T, out, 128, 0);
}

// Round 23
// 176.220 us; speedup vs baseline: 1.0215x; 1.0215x over previous
//
#include <hip/hip_runtime.h>
#include <hip/hip_bf16.h>
#include <cstdint>

// ---------------------------------------------------------------------------
// GABlock, channel-last bf16-MFMA pipeline.  FINAL (R20 configuration).
// - NCHW->channel-last bf16 ingest; all convs as bf16-MFMA GEMMs with fused
//   epilogues (gelu / channel-LN+residual / fp32-NCHW full-line stores).
// - Grid branch: merged qkv+gp GEMM; BOTH attentions fused in one kernel
//   (O1 held in LDS); a1 projection algebraically folded into a2 (A2@A1).
// - Window branches: block-diagonal qkv GEMM (window-ordered, shift folded)
//   + barrier-free per-wave MFMA window attention.
// - Bias tables bf16 [h][m][q] (halves gattn2's L2 working set).
// ---------------------------------------------------------------------------

typedef __attribute__((ext_vector_type(8))) short bf8_t;   // 8 bf16 (4 VGPR)
typedef __attribute__((ext_vector_type(4))) float f4_t;    // 4 f32 acc

__device__ __forceinline__ float bf2f(unsigned short u) {
  union { unsigned int i; float f; } x; x.i = ((unsigned int)u) << 16; return x.f;
}
__device__ __forceinline__ unsigned short f2bf(float f) {
  union { float f; unsigned int i; } x; x.f = f;
  unsigned int r = x.i + 0x7FFFu + ((x.i >> 16) & 1u);
  return (unsigned short)(r >> 16);
}
// HW packed f32x2 -> bf16x2 (RNE).
__device__ __forceinline__ unsigned int pk2(float a, float b) {
  unsigned int d;
  asm("v_cvt_pk_bf16_f32 %0, %1, %2" : "=v"(d) : "v"(a), "v"(b));
  return d;
}

#define MB (1048576L)

// ---------------- fused setup: weights->bf16, rpbT, wq2, pos MLP -----------
__global__ void setup_k(
    const float* __restrict__ w0, const float* __restrict__ w1,
    const float* __restrict__ w2, const float* __restrict__ w3,
    const float* __restrict__ w4, const float* __restrict__ w5,
    const float* __restrict__ w6,
    const float* __restrict__ qkv_b, const float* __restrict__ gp_b,
    const float* __restrict__ sw_w, const float* __restrict__ sw_b,
    const float* __restrict__ wn_w, const float* __restrict__ wn_b,
    const float* __restrict__ sw_rpb, const float* __restrict__ wn_rpb,
    const float* __restrict__ pw1, const float* __restrict__ pb1,
    const float* __restrict__ pw2, const float* __restrict__ pb2,
    const float* __restrict__ pw3, const float* __restrict__ pb3,
    unsigned short* __restrict__ wbf, float* __restrict__ biasQG,
    unsigned short* __restrict__ wq2, float* __restrict__ b192,
    float* __restrict__ rpbT_sw, float* __restrict__ rpbT_wn,
    float* __restrict__ ptab) {
  const float QS = 0.35355339059327373f;
  int t = blockIdx.x * 256 + threadIdx.x;
  if (t < 106496) {
    const float* src; int off; float sc = 1.0f;
    if (t < 12288)      { src = w0; off = 0; }
    else if (t < 16384) { src = w1; off = 12288; sc = 0.25f; }
    else if (t < 20480) { src = w2; off = 16384; }
    else if (t < 24576) { src = w3; off = 20480; }
    else if (t < 40960) { src = w4; off = 24576; }
    else if (t < 73728) { src = w5; off = 40960; }
    else                { src = w6; off = 73728; }
    wbf[t] = f2bf(src[t - off] * sc);
  } else if (t < 106752) {
    int i = t - 106496;
    biasQG[i] = i < 192 ? qkv_b[i] : gp_b[i - 192] * 0.25f;
  } else if (t < 119040) {
    int i = t - 106752;
    int row = i >> 6, col = i & 63;
    float v = 0.0f;
    if (row < 96) { if (col < 32) v = sw_w[row * 32 + col]; }
    else          { if (col >= 32) v = wn_w[(row - 96) * 32 + col - 32]; }
    if ((row % 96) < 32) v *= QS;
    wq2[i] = f2bf(v);
  } else if (t < 119232) {
    int i = t - 119040;
    float v = i < 96 ? sw_b[i] : wn_b[i - 96];
    if ((i % 96) < 32) v *= QS;
    b192[i] = v;
  } else if (t < 152000) {
    int i = t - 119232;
    const float* rpb = i < 16384 ? sw_rpb : wn_rpb;
    float* dst = i < 16384 ? rpbT_sw : rpbT_wn;
    int j = i & 16383;
    int h = j >> 12, r = j & 4095, m = r >> 6, n = r & 63;
    int idx = ((n >> 3) - (m >> 3) + 7) * 15 + ((n & 7) - (m & 7) + 7);
    dst[j] = rpb[idx * 4 + h];
  } else if (t < 152961) {
    int j = t - 152000;
    float chv = (float)(j / 31) - 15.0f;
    float cwv = (float)(j % 31) - 15.0f;
    float t1[16], t2[16];
#pragma unroll
    for (int i = 0; i < 16; ++i) {
      float s = fmaf(pw1[i * 2], chv, fmaf(pw1[i * 2 + 1], cwv, pb1[i]));
      t1[i] = fmaxf(s, 0.0f);
    }
#pragma unroll
    for (int i = 0; i < 16; ++i) {
      float s = pb2[i];
#pragma unroll
      for (int k = 0; k < 16; ++k) s = fmaf(pw2[i * 16 + k], t1[k], s);
      t2[i] = fmaxf(s, 0.0f);
    }
#pragma unroll
    for (int hh = 0; hh < 4; ++hh) {
      float s = pb3[hh];
#pragma unroll
      for (int k = 0; k < 16; ++k) s = fmaf(pw3[hh * 16 + k], t2[k], s);
      ptab[j * 4 + hh] = s;
    }
  }
}

// A21 = A2 @ A1 (64x64, fp32 accum -> bf16 into wbf a2 slot); b21 = A2@a1_b + a2_b
__global__ void wfold_k(const float* __restrict__ a1w, const float* __restrict__ a1b,
                        const float* __restrict__ a2w, const float* __restrict__ a2b,
                        unsigned short* __restrict__ w21, float* __restrict__ b21) {
  int t = blockIdx.x * 256 + threadIdx.x;   // 4096
  int co = t >> 6, ci = t & 63;
  float s = 0.0f;
#pragma unroll 8
  for (int k = 0; k < 64; ++k) s = fmaf(a2w[co * 64 + k], a1w[k * 64 + ci], s);
  w21[t] = f2bf(s);
  if (t < 64) {
    float b = a2b[t];
#pragma unroll 8
    for (int k = 0; k < 64; ++k) b = fmaf(a2w[t * 64 + k], a1b[k], b);
    b21[t] = b;
  }
}

// pbTh[h][m][q] bf16
__global__ void pbT_k(const float* __restrict__ table, unsigned short* __restrict__ pbTh) {
  int t = blockIdx.x * 256 + threadIdx.x;   // 262144
  int hh = t >> 16;
  int r = t & 65535;
  int m = r >> 8;
  int q = r & 255;
  int idx = ((q >> 4) - (m >> 4) + 15) * 31 + ((q & 15) - (m & 15) + 15);
  pbTh[t] = f2bf(table[idx * 4 + hh]);
}

// ---------------- NCHW fp32 -> channel-last bf16 ---------------------------
__global__ __launch_bounds__(256) void tin_k(const float* __restrict__ x,
                                             unsigned short* __restrict__ xTb) {
  __shared__ float tile[64][132];
  const int b = blockIdx.z, px0 = blockIdx.x * 64, tid = threadIdx.x;
#pragma unroll
  for (int i = 0; i < 8; ++i) {
    int e = i * 256 + tid;
    int c = e >> 4, p4 = (e & 15) * 4;
    float4 v = *(const float4*)(x + (((size_t)(b * 128 + c)) << 14) + px0 + p4);
    tile[p4][c] = v.x; tile[p4 + 1][c] = v.y; tile[p4 + 2][c] = v.z; tile[p4 + 3][c] = v.w;
  }
  __syncthreads();
#pragma unroll
  for (int i = 0; i < 8; ++i) {
    int e = i * 256 + tid;
    int px = e >> 5, c4 = (e & 31) * 4;
    uint2 w = {pk2(tile[px][c4], tile[px][c4 + 1]), pk2(tile[px][c4 + 2], tile[px][c4 + 3])};
    *(uint2*)(xTb + ((size_t)(b * 16384 + px0 + px)) * 128 + c4) = w;
  }
}

// ---------------- generic bf16-MFMA GEMM -----------------------------------
// EPI: 0 plain->bf16, 1 gelu->bf16, 2 cLN+res(bf16)->bf16,
//      3 cLN+res(bf16)+res2(bf16)->f32 NCHW full-line stores
template <int NF, int KC, int EPI, int OSHUF>
__global__ __launch_bounds__(256) void gemm_k(
    const unsigned short* __restrict__ A, int a_rs, int a_c0,
    const unsigned short* __restrict__ W, const float* __restrict__ bias,
    const float* __restrict__ g, const float* __restrict__ bb,
    const unsigned short* __restrict__ resf, const unsigned short* __restrict__ resb,
    void* __restrict__ out, int o_rs, int o_c0) {
  __shared__ __align__(16) char Asw[128 * 128];
  __shared__ __align__(16) char Bsw[NF * 16 * 128];
  const int tid = threadIdx.x;
  const int lane = tid & 63, wv = tid >> 6, wpx = wv * 32;
  const int lr = lane & 15, lg = lane >> 4;
  const int px0 = blockIdx.x * 128;
  const int co0 = blockIdx.y * (NF * 16);

  f4_t acc[2][NF];
#pragma unroll
  for (int mf = 0; mf < 2; ++mf)
#pragma unroll
    for (int nf = 0; nf < NF; ++nf) acc[mf][nf] = (f4_t){0.f, 0.f, 0.f, 0.f};

  for (int kc = 0; kc < KC; ++kc) {
    const int k0 = kc * 64;
    if (kc) __syncthreads();
#pragma unroll
    for (int i = 0; i < 4; ++i) {
      int e = i * 256 + tid;
      int row = e >> 3, q8 = e & 7;
      const unsigned short* src = A + (size_t)(px0 + row) * a_rs + a_c0 + k0 + q8 * 8;
      *(uint4*)(Asw + row * 128 + ((q8 ^ (row & 7)) << 4)) = *(const uint4*)src;
    }
#pragma unroll
    for (int i = 0; i < NF / 2; ++i) {
      int e = i * 256 + tid;
      int row = e >> 3, q8 = e & 7;
      const unsigned short* src = W + (size_t)(co0 + row) * (KC * 64) + k0 + q8 * 8;
      *(uint4*)(Bsw + row * 128 + ((q8 ^ (row & 7)) << 4)) = *(const uint4*)src;
    }
    __syncthreads();
#pragma unroll
    for (int ks = 0; ks < 2; ++ks) {
      const int xk = (((ks * 4) + lg) ^ (lane & 7)) << 4;
      bf8_t av[2], bv[NF];
#pragma unroll
      for (int mf = 0; mf < 2; ++mf)
        av[mf] = *(const bf8_t*)(Asw + (wpx + mf * 16 + lr) * 128 + xk);
#pragma unroll
      for (int nf = 0; nf < NF; ++nf)
        bv[nf] = *(const bf8_t*)(Bsw + (nf * 16 + lr) * 128 + xk);
#pragma unroll
      for (int mf = 0; mf < 2; ++mf)
#pragma unroll
        for (int nf = 0; nf < NF; ++nf)
          acc[mf][nf] = __builtin_amdgcn_mfma_f32_16x16x32_bf16(av[mf], bv[nf], acc[mf][nf], 0, 0, 0);
    }
  }

  float bco[NF];
#pragma unroll
  for (int nf = 0; nf < NF; ++nf) bco[nf] = bias[co0 + nf * 16 + lr];

  if constexpr (EPI >= 2) {
    float gv[NF], bbv[NF];
#pragma unroll
    for (int nf = 0; nf < NF; ++nf) { gv[nf] = g[nf * 16 + lr]; bbv[nf] = bb[nf * 16 + lr]; }
#pragma unroll
    for (int mf = 0; mf < 2; ++mf)
#pragma unroll
      for (int nf = 0; nf < NF; ++nf)
#pragma unroll
        for (int r = 0; r < 4; ++r) acc[mf][nf][r] += bco[nf];
#pragma unroll
    for (int mf = 0; mf < 2; ++mf) {
      float mus[4], rss[4];
#pragma unroll
      for (int r = 0; r < 4; ++r) {
        float s = 0.f, q = 0.f;
#pragma unroll
        for (int nf = 0; nf < NF; ++nf) {
          float v = acc[mf][nf][r];
          s += v; q += v * v;
        }
#pragma unroll
        for (int msk = 1; msk < 16; msk <<= 1) {
          s += __shfl_xor(s, msk);
          q += __shfl_xor(q, msk);
        }
        float mu = s * (1.0f / 128.0f);
        float var = q * (1.0f / 128.0f) - mu * mu;
        mus[r] = mu;
        rss[r] = rsqrtf(var + 1e-5f);
      }
      if constexpr (EPI == 2) {
#pragma unroll
        for (int r = 0; r < 4; ++r) {
          int px_e = px0 + wpx + mf * 16 + lg * 4 + r;
          const unsigned short* xr = resf + (size_t)px_e * 128 + lr;
          unsigned short* op = (unsigned short*)out + (size_t)px_e * o_rs + lr;
#pragma unroll
          for (int nf = 0; nf < NF; ++nf) {
            float v = (acc[mf][nf][r] - mus[r]) * rss[r] * gv[nf] + bbv[nf] + bf2f(xr[nf * 16]);
            op[nf * 16] = f2bf(v);
          }
        }
      } else {  // EPI == 3: fp32 NCHW, one float4 (4 px) per channel per thread
        int pxb = px0 + wpx + mf * 16 + lg * 4;
        int b_ = pxb >> 14, p_ = pxb & 16383;
#pragma unroll
        for (int nf = 0; nf < NF; ++nf) {
          int ch = lr + nf * 16;
          float vr[4];
#pragma unroll
          for (int r = 0; r < 4; ++r) {
            float xv  = bf2f(resf[(size_t)(pxb + r) * 128 + ch]);
            float x2v = bf2f(resb[(size_t)(pxb + r) * 128 + ch]);
            vr[r] = (acc[mf][nf][r] - mus[r]) * rss[r] * gv[nf] + bbv[nf] + xv + x2v;
          }
          float4 v4 = {vr[0], vr[1], vr[2], vr[3]};
          *(float4*)((float*)out + (((size_t)(b_ * 128 + ch)) << 14) + p_) = v4;
        }
      }
    }
  } else {
#pragma unroll
    for (int mf = 0; mf < 2; ++mf) {
#pragma unroll
      for (int r = 0; r < 4; ++r) {
        int px_e = px0 + wpx + mf * 16 + lg * 4 + r;
        size_t orow;
        int cadj = co0;
        if constexpr (OSHUF == 0) {
          orow = (size_t)px_e;
        } else if constexpr (OSHUF == 1) {
          int b = px_e >> 14, p = px_e & 16383, hh = p >> 7, w_ = p & 127;
          orow = (size_t)(b * 64 + (hh & 7) * 8 + (w_ & 7)) * 256 + ((hh >> 3) * 16 + (w_ >> 3));
        } else if constexpr (OSHUF == 2) {
          int gbb = px_e >> 8, n = px_e & 255;
          int b = gbb >> 6, ih = (gbb >> 3) & 7, iw = gbb & 7;
          orow = (size_t)b * 16384 + ((n >> 4) * 8 + ih) * 128 + (n & 15) * 8 + iw;
        } else {  // window-order: br0 = sw(shift 4), br1 = wn(shift 0)
          int brx = (co0 >= 96);
          int b = px_e >> 14, p = px_e & 16383, hh = p >> 7, w_ = p & 127;
          int sh = brx ? 0 : 4;
          int h2 = (hh - sh) & 127, w2_ = (w_ - sh) & 127;
          orow = (size_t)brx * 65536 + (size_t)b * 16384 +
                 (size_t)(((h2 >> 3) * 16 + (w2_ >> 3)) * 64 + (h2 & 7) * 8 + (w2_ & 7));
          cadj = co0 - brx * 96;
        }
        unsigned short* op = (unsigned short*)out + orow * o_rs + o_c0 + cadj + lr;
#pragma unroll
        for (int nf = 0; nf < NF; ++nf) {
          float v = acc[mf][nf][r] + bco[nf];
          if constexpr (EPI == 1) v = 0.5f * v * (1.0f + erff(v * 0.7071067811865475f));
          op[nf * 16] = f2bf(v);
        }
      }
    }
  }
}

// ---------------- fused double grid attention (8 waves x 32 queries) -------
// Block = (gb, h), 512 threads. Phase 1: O1 = softmax(G K^T + B) V  -> LDS.
// Phase 2: O2 = softmax(q G^T + B) O1 -> global. Bias table bf16 [h][m][q].
__global__ __launch_bounds__(512, 4) void gattn2_k(
    const unsigned short* __restrict__ qgT,
    const unsigned short* __restrict__ pbTh, unsigned short* __restrict__ outb) {
  __shared__ __align__(16) unsigned short K_lds[256 * 16];   // 8 KB  [m][16d]
  __shared__ __align__(16) unsigned short G_lds[256 * 16];   // 8 KB  [m][16d]
  __shared__ __align__(16) unsigned short Vt[16 * 256];      // 8 KB  swz [d][m]
  __shared__ __align__(16) unsigned short Vt2[16 * 256];     // 8 KB  swz [d][m] (O1)
  __shared__ __align__(16) unsigned short P_lds[8 * 32 * 32];// 16 KB per-wave swz
  const int gb = blockIdx.x, h = blockIdx.y, tid = threadIdx.x;
  const int lane = tid & 63, wv = tid >> 6;        // wv in [0,8)
  const int lr = lane & 15, lg = lane >> 4;
  const int q0 = wv * 32;
  const f4_t z4 = {0.f, 0.f, 0.f, 0.f};
  const bf8_t bz = {0, 0, 0, 0, 0, 0, 0, 0};
  unsigned short* Pw = &P_lds[wv * 32 * 32];
  const unsigned short* bpm_base = pbTh + ((size_t)(h * 256) << 8);

  // ---- stage K rows + G rows (threads 0-255) and V^T (threads 256-511) ----
  if (tid < 256) {
    const unsigned short* kp = qgT + (size_t)(gb * 256 + tid) * 256 + 64 + h * 16;
    *(uint4*)&K_lds[tid * 16]     = *(const uint4*)kp;
    *(uint4*)&K_lds[tid * 16 + 8] = *(const uint4*)(kp + 8);
    const unsigned short* gp = qgT + (size_t)(gb * 256 + tid) * 256 + 192 + h * 16;
    *(uint4*)&G_lds[tid * 16]     = *(const uint4*)gp;
    *(uint4*)&G_lds[tid * 16 + 8] = *(const uint4*)(gp + 8);
  } else {
    int m = tid - 256;
    const unsigned short* vp = qgT + (size_t)(gb * 256 + m) * 256 + 128 + h * 16;
    uint4 va = *(const uint4*)vp;
    uint4 vb = *(const uint4*)(vp + 8);
    unsigned int w8[8] = {va.x, va.y, va.z, va.w, vb.x, vb.y, vb.z, vb.w};
    int chb = m >> 3, wi = m & 7;
#pragma unroll
    for (int w = 0; w < 8; ++w) {
      int d0 = 2 * w, d1 = 2 * w + 1;
      Vt[d0 * 256 + ((chb ^ (d0 & 7)) << 3) + wi] = (unsigned short)(w8[w] & 0xffff);
      Vt[d1 * 256 + ((chb ^ (d1 & 7)) << 3) + wi] = (unsigned short)(w8[w] >> 16);
    }
  }
  __syncthreads();

  // ================= phase 1: O1 = softmax(G K^T + B) V =================
  {
    bf8_t bq[2];
#pragma unroll
    for (int qt = 0; qt < 2; ++qt) {
      bq[qt] = bz;
      if (lg < 2)
        bq[qt] = *(const bf8_t*)&G_lds[(q0 + qt * 16 + lr) * 16 + lg * 8];
    }
    f4_t oacc[2];
    float lrun[2];
#pragma unroll
    for (int qt = 0; qt < 2; ++qt) { oacc[qt] = z4; lrun[qt] = 0.0f; }

    for (int m0 = 0; m0 < 256; m0 += 32) {
      bf8_t ak0 = bz, ak1 = bz;
      if (lg < 2) {
        ak0 = *(const bf8_t*)&K_lds[(m0 + lr) * 16 + lg * 8];
        ak1 = *(const bf8_t*)&K_lds[(m0 + 16 + lr) * 16 + lg * 8];
      }
      bf8_t av = *(const bf8_t*)&Vt[lr * 256 + ((((m0 >> 3) + lg) ^ (lr & 7)) << 3)];

#pragma unroll
      for (int qt = 0; qt < 2; ++qt) {
        const unsigned short* bpm = bpm_base + ((size_t)(m0 + lg * 4) << 8) + q0 + qt * 16 + lr;
        f4_t c0v = {bf2f(bpm[0]), bf2f(bpm[256]), bf2f(bpm[512]), bf2f(bpm[768])};
        f4_t c1v = {bf2f(bpm[4096]), bf2f(bpm[4352]), bf2f(bpm[4608]), bf2f(bpm[4864])};
        f4_t st0 = __builtin_amdgcn_mfma_f32_16x16x32_bf16(ak0, bq[qt], c0v, 0, 0, 0);
        f4_t st1 = __builtin_amdgcn_mfma_f32_16x16x32_bf16(ak1, bq[qt], c1v, 0, 0, 0);
        float p0[4], p1[4], ls = 0.0f;
#pragma unroll
        for (int r = 0; r < 4; ++r) {
          p0[r] = __expf(st0[r]);
          p1[r] = __expf(st1[r]);
          ls += p0[r] + p1[r];
        }
        ls += __shfl_xor(ls, 16);
        ls += __shfl_xor(ls, 32);
        lrun[qt] += ls;
        int row = qt * 16 + lr;
        int rw3 = row & 3;
        uint2 w0 = {pk2(p0[0], p0[1]), pk2(p0[2], p0[3])};
        uint2 w1 = {pk2(p1[0], p1[1]), pk2(p1[2], p1[3])};
        *(uint2*)&Pw[row * 32 + ((((lg >> 1)) ^ rw3) << 3) + (lg & 1) * 4]     = w0;
        *(uint2*)&Pw[row * 32 + (((2 + (lg >> 1)) ^ rw3) << 3) + (lg & 1) * 4] = w1;
      }
#pragma unroll
      for (int qt = 0; qt < 2; ++qt) {
        int row = qt * 16 + lr;
        bf8_t bp = *(const bf8_t*)&Pw[row * 32 + ((lg ^ (row & 3)) << 3)];
        oacc[qt] = __builtin_amdgcn_mfma_f32_16x16x32_bf16(av, bp, oacc[qt], 0, 0, 0);
      }
    }
    // O1 -> Vt2 (swizzled [d][m]): lane holds O^T[d = lg*4+r][m = q0+qt*16+lr]
#pragma unroll
    for (int qt = 0; qt < 2; ++qt) {
      float inv = 1.0f / lrun[qt];
      int m = q0 + qt * 16 + lr;
      int chb = m >> 3, wi = m & 7;
      unsigned int pA = pk2(oacc[qt][0] * inv, oacc[qt][1] * inv);
      unsigned int pB = pk2(oacc[qt][2] * inv, oacc[qt][3] * inv);
      int d0 = lg * 4;
      Vt2[(d0    ) * 256 + ((chb ^ ((d0    ) & 7)) << 3) + wi] = (unsigned short)(pA & 0xffff);
      Vt2[(d0 + 1) * 256 + ((chb ^ ((d0 + 1) & 7)) << 3) + wi] = (unsigned short)(pA >> 16);
      Vt2[(d0 + 2) * 256 + ((chb ^ ((d0 + 2) & 7)) << 3) + wi] = (unsigned short)(pB & 0xffff);
      Vt2[(d0 + 3) * 256 + ((chb ^ ((d0 + 3) & 7)) << 3) + wi] = (unsigned short)(pB >> 16);
    }
  }
  __syncthreads();

  // ================= phase 2: O2 = softmax(q G^T + B) O1 =================
  {
    bf8_t bq[2];
#pragma unroll
    for (int qt = 0; qt < 2; ++qt) {
      bq[qt] = bz;
      if (lg < 2)
        bq[qt] = *(const bf8_t*)(qgT + (size_t)(gb * 256 + q0 + qt * 16 + lr) * 256 + h * 16 + lg * 8);
    }
    f4_t oacc[2];
    float lrun[2];
#pragma unroll
    for (int qt = 0; qt < 2; ++qt) { oacc[qt] = z4; lrun[qt] = 0.0f; }

    for (int m0 = 0; m0 < 256; m0 += 32) {
      bf8_t ak0 = bz, ak1 = bz;
      if (lg < 2) {
        ak0 = *(const bf8_t*)&G_lds[(m0 + lr) * 16 + lg * 8];
        ak1 = *(const bf8_t*)&G_lds[(m0 + 16 + lr) * 16 + lg * 8];
      }
      bf8_t av = *(const bf8_t*)&Vt2[lr * 256 + ((((m0 >> 3) + lg) ^ (lr & 7)) << 3)];

#pragma unroll
      for (int qt = 0; qt < 2; ++qt) {
        const unsigned short* bpm = bpm_base + ((size_t)(m0 + lg * 4) << 8) + q0 + qt * 16 + lr;
        f4_t c0v = {bf2f(bpm[0]), bf2f(bpm[256]), bf2f(bpm[512]), bf2f(bpm[768])};
        f4_t c1v = {bf2f(bpm[4096]), bf2f(bpm[4352]), bf2f(bpm[4608]), bf2f(bpm[4864])};
        f4_t st0 = __builtin_amdgcn_mfma_f32_16x16x32_bf16(ak0, bq[qt], c0v, 0, 0, 0);
        f4_t st1 = __builtin_amdgcn_mfma_f32_16x16x32_bf16(ak1, bq[qt], c1v, 0, 0, 0);
        float p0[4], p1[4], ls = 0.0f;
#pragma unroll
        for (int r = 0; r < 4; ++r) {
          p0[r] = __expf(st0[r]);
          p1[r] = __expf(st1[r]);
          ls += p0[r] + p1[r];
        }
        ls += __shfl_xor(ls, 16);
        ls += __shfl_xor(ls, 32);
        lrun[qt] += ls;
        int row = qt * 16 + lr;
        int rw3 = row & 3;
        uint2 w0 = {pk2(p0[0], p0[1]), pk2(p0[2], p0[3])};
        uint2 w1 = {pk2(p1[0], p1[1]), pk2(p1[2], p1[3])};
        *(uint2*)&Pw[row * 32 + ((((lg >> 1)) ^ rw3) << 3) + (lg & 1) * 4]     = w0;
        *(uint2*)&Pw[row * 32 + (((2 + (lg >> 1)) ^ rw3) << 3) + (lg & 1) * 4] = w1;
      }
#pragma unroll
      for (int qt = 0; qt < 2; ++qt) {
        int row = qt * 16 + lr;
        bf8_t bp = *(const bf8_t*)&Pw[row * 32 + ((lg ^ (row & 3)) << 3)];
        oacc[qt] = __builtin_amdgcn_mfma_f32_16x16x32_bf16(av, bp, oacc[qt], 0, 0, 0);
      }
    }
#pragma unroll
    for (int qt = 0; qt < 2; ++qt) {
      float inv = 1.0f / lrun[qt];
      uint2 o;
      o.x = pk2(oacc[qt][0] * inv, oacc[qt][1] * inv);
      o.y = pk2(oacc[qt][2] * inv, oacc[qt][3] * inv);
      unsigned short* op = outb + (size_t)(gb * 256 + q0 + qt * 16 + lr) * 64 + h * 16 + lg * 4;
      *(uint2*)op = o;
    }
  }
}

// ---------------- MFMA swin window attention (barrier-free) ----------------
__global__ __launch_bounds__(256) void swat_k(
    const unsigned short* __restrict__ qkv2,
    const float* __restrict__ rpbT_sw, const float* __restrict__ rpbT_wn,
    const float* __restrict__ sw_pw, const float* __restrict__ sw_pb,
    const float* __restrict__ wn_pw, const float* __restrict__ wn_pb,
    unsigned short* __restrict__ yT) {
  __shared__ __align__(16) unsigned short Vt[4 * 8 * 64];
  __shared__ __align__(16) unsigned short Pt[4 * 64 * 64];
  __shared__ __align__(16) unsigned short aoT[4 * 64 * 32];
  const int tid = threadIdx.x, lane = tid & 63, wv = tid >> 6;
  const int lr = lane & 15, lg = lane >> 4;
  const int br = blockIdx.y;
  const int win = blockIdx.x * 4 + wv;
  const int b = win >> 8, wl = win & 255, wh = wl >> 4, ww = wl & 15;
  const float* rpbT = br ? rpbT_wn : rpbT_sw;
  const float* pw   = br ? wn_pw : sw_pw;
  const float* pb   = br ? wn_pb : sw_pb;
  const int shift = br ? 0 : 4;
  const int yc0 = br ? 0 : 32;
  const bool edge = (shift > 0) && (wh == 15 || ww == 15);

  const unsigned short* qw = qkv2 + (size_t)br * 65536 * 96 + (size_t)win * 64 * 96;
  const f4_t z4 = {0.f, 0.f, 0.f, 0.f};
  const bf8_t bz = {0, 0, 0, 0, 0, 0, 0, 0};
  unsigned short* Vw = &Vt[wv * 8 * 64];
  unsigned short* Pw = &Pt[wv * 64 * 64];
  unsigned short* aw_ = &aoT[wv * 64 * 32];

#pragma unroll 1
  for (int h = 0; h < 4; ++h) {
    {
      uint4 v = *(const uint4*)(qw + lane * 96 + 64 + h * 8);
      unsigned int w4[4] = {v.x, v.y, v.z, v.w};
      int chb = lane >> 3, wi = lane & 7;
#pragma unroll
      for (int j = 0; j < 4; ++j) {
        int d0 = 2 * j, d1 = 2 * j + 1;
        Vw[d0 * 64 + ((chb ^ (d0 & 7)) << 3) + wi] = (unsigned short)(w4[j] & 0xffff);
        Vw[d1 * 64 + ((chb ^ (d1 & 7)) << 3) + wi] = (unsigned short)(w4[j] >> 16);
      }
    }
    bf8_t bq[4];
#pragma unroll
    for (int nt = 0; nt < 4; ++nt) {
      bq[nt] = bz;
      if (lg == 0) bq[nt] = *(const bf8_t*)(qw + (nt * 16 + lr) * 96 + h * 8);
    }
    f4_t st[4][4];
#pragma unroll
    for (int mt = 0; mt < 4; ++mt) {
      bf8_t ak = bz;
      if (lg == 0) ak = *(const bf8_t*)(qw + (mt * 16 + lr) * 96 + 32 + h * 8);
#pragma unroll
      for (int nt = 0; nt < 4; ++nt) {
        const float* rp = rpbT + h * 4096 + (mt * 16 + lg * 4) * 64 + nt * 16 + lr;
        f4_t cb = {rp[0], rp[64], rp[128], rp[192]};
        st[mt][nt] = __builtin_amdgcn_mfma_f32_16x16x32_bf16(ak, bq[nt], cb, 0, 0, 0);
      }
    }
#pragma unroll
    for (int nt = 0; nt < 4; ++nt) {
      float sv[16];
#pragma unroll
      for (int mt = 0; mt < 4; ++mt)
#pragma unroll
        for (int r = 0; r < 4; ++r) sv[mt * 4 + r] = st[mt][nt][r];
      if (edge) {
        int n = nt * 16 + lr;
        int regn = ((wh < 15) ? 0 : (((n >> 3) < 4) ? 1 : 2)) * 3 +
                   ((ww < 15) ? 0 : (((n & 7) < 4) ? 1 : 2));
#pragma unroll
        for (int mt = 0; mt < 4; ++mt)
#pragma unroll
          for (int r = 0; r < 4; ++r) {
            int m = mt * 16 + lg * 4 + r;
            int regm = ((wh < 15) ? 0 : (((m >> 3) < 4) ? 1 : 2)) * 3 +
                       ((ww < 15) ? 0 : (((m & 7) < 4) ? 1 : 2));
            if (regm != regn) sv[mt * 4 + r] -= 100.0f;
          }
      }
      float l = 0.0f;
#pragma unroll
      for (int i = 0; i < 16; ++i) {
        sv[i] = __expf(sv[i]);
        l += sv[i];
      }
      l += __shfl_xor(l, 16);
      l += __shfl_xor(l, 32);
      float inv = 1.0f / l;
      int row = nt * 16 + lr, rw7 = lr & 7;
#pragma unroll
      for (int mt = 0; mt < 4; ++mt) {
        uint2 w = {pk2(sv[mt * 4] * inv, sv[mt * 4 + 1] * inv),
                   pk2(sv[mt * 4 + 2] * inv, sv[mt * 4 + 3] * inv)};
        *(uint2*)&Pw[row * 64 + (((2 * mt + (lg >> 1)) ^ rw7) << 3) + (lg & 1) * 4] = w;
      }
    }
    f4_t oa[4] = {z4, z4, z4, z4};
#pragma unroll
    for (int ks = 0; ks < 2; ++ks) {
      bf8_t av = bz;
      if (lr < 8) av = *(const bf8_t*)&Vw[lr * 64 + (((4 * ks + lg) ^ (lr & 7)) << 3)];
#pragma unroll
      for (int nt = 0; nt < 4; ++nt) {
        int row = nt * 16 + lr;
        bf8_t bp = *(const bf8_t*)&Pw[row * 64 + (((4 * ks + lg) ^ (lr & 7)) << 3)];
        oa[nt] = __builtin_amdgcn_mfma_f32_16x16x32_bf16(av, bp, oa[nt], 0, 0, 0);
      }
    }
    if (lg < 2) {
#pragma unroll
      for (int nt = 0; nt < 4; ++nt) {
        uint2 w = {pk2(oa[nt][0], oa[nt][1]), pk2(oa[nt][2], oa[nt][3])};
        int row = nt * 16 + lr;
        *(uint2*)&aw_[row * 32 + ((h ^ (lr & 3)) << 3) + lg * 4] = w;
      }
    }
  }

#pragma unroll
  for (int mt = 0; mt < 2; ++mt) {
    const float* wr = pw + (mt * 16 + lr) * 32 + lg * 8;
    float4 a0 = *(const float4*)wr, a1 = *(const float4*)(wr + 4);
    union { uint4 u; bf8_t v; } aw;
    aw.u.x = pk2(a0.x, a0.y); aw.u.y = pk2(a0.z, a0.w);
    aw.u.z = pk2(a1.x, a1.y); aw.u.w = pk2(a1.z, a1.w);
    float pb0 = pb[mt * 16 + lg * 4], pb1 = pb[mt * 16 + lg * 4 + 1];
    float pb2 = pb[mt * 16 + lg * 4 + 2], pb3 = pb[mt * 16 + lg * 4 + 3];
#pragma unroll
    for (int nt = 0; nt < 4; ++nt) {
      int row = nt * 16 + lr;
      bf8_t bo = *(const bf8_t*)&aw_[row * 32 + ((lg ^ (lr & 3)) << 3)];
      f4_t po = __builtin_amdgcn_mfma_f32_16x16x32_bf16(aw.v, bo, z4, 0, 0, 0);
      int n = nt * 16 + lr;
      int hdst = (wh * 8 + (n >> 3) + shift) & 127;
      int wdst = (ww * 8 + (n & 7) + shift) & 127;
      uint2 w = {pk2(po[0] + pb0, po[1] + pb1), pk2(po[2] + pb2, po[3] + pb3)};
      *(uint2*)(yT + ((size_t)(b * 16384 + hdst * 128 + wdst)) * 128 + yc0 + mt * 16 + lg * 4) = w;
    }
  }
}

// ---------------------------------------------------------------------------
extern "C" void kernel_launch(void* const* d_in, const int* in_sizes, int n_in,
                              void* d_out, int out_size, void* d_ws, size_t ws_size,
                              hipStream_t stream) {
  (void)in_sizes; (void)n_in; (void)out_size; (void)ws_size;
  const float* x        = (const float*)d_in[0];
  const float* ln_g     = (const float*)d_in[1];
  const float* ln_b     = (const float*)d_in[2];
  const float* ga_qkv_w = (const float*)d_in[3];
  const float* ga_qkv_b = (const float*)d_in[4];
  const float* ga_gp_w  = (const float*)d_in[5];
  const float* ga_gp_b  = (const float*)d_in[6];
  const float* pos_w1   = (const float*)d_in[7];
  const float* pos_b1   = (const float*)d_in[8];
  const float* pos_w2   = (const float*)d_in[9];
  const float* pos_b2   = (const float*)d_in[10];
  const float* pos_w3   = (const float*)d_in[11];
  const float* pos_b3   = (const float*)d_in[12];
  const float* a1_pw    = (const float*)d_in[13];
  const float* a1_pb    = (const float*)d_in[14];
  const float* a2_pw    = (const float*)d_in[15];
  const float* a2_pb    = (const float*)d_in[16];
  const float* sw_qkv_w = (const float*)d_in[17];
  const float* sw_qkv_b = (const float*)d_in[18];
  const float* sw_rpb   = (const float*)d_in[19];
  const float* sw_pw    = (const float*)d_in[20];
  const float* sw_pb    = (const float*)d_in[21];
  const float* wn_qkv_w = (const float*)d_in[22];
  const float* wn_qkv_b = (const float*)d_in[23];
  const float* wn_rpb   = (const float*)d_in[24];
  const float* wn_pw    = (const float*)d_in[25];
  const float* wn_pb    = (const float*)d_in[26];
  const float* fc_w     = (const float*)d_in[27];
  const float* fc_b     = (const float*)d_in[28];
  const float* n2_g     = (const float*)d_in[29];
  const float* n2_b     = (const float*)d_in[30];
  const float* m1_w     = (const float*)d_in[31];
  const float* m1_b     = (const float*)d_in[32];
  const float* m2_w     = (const float*)d_in[33];
  const float* m2_b     = (const float*)d_in[34];
  float* out = (float*)d_out;
  char* base = (char*)d_ws;

  unsigned short* xTb    = (unsigned short*)(base);           // 16 MB
  unsigned short* qgT    = (unsigned short*)(base + 16 * MB); // 32 MB [px][256: q|k|v|g]
  unsigned short* t2T    = (unsigned short*)(base + 48 * MB); //  8 MB
  unsigned short* yT     = (unsigned short*)(base + 64 * MB); // 16 MB
  unsigned short* x2T    = (unsigned short*)(base + 80 * MB); // 16 MB
  unsigned short* qkv2   = (unsigned short*)(base + 16 * MB); // 24 MB alias (after gattn)
  unsigned short* hT     = (unsigned short*)(base + 16 * MB); // 32 MB alias (after swat)
  unsigned short* pbTh   = (unsigned short*)(base + 96 * MB); // 512 KB bf16 [h][m][q]
  float*          ptab   = (float*)(base + 97 * MB);          // 16 KB
  float*          rpbT_sw= (float*)(base + 97 * MB + 65536);  // 64 KB f32
  float*          rpbT_wn= (float*)(base + 97 * MB + 131072); // 64 KB f32
  unsigned short* wq2bf  = (unsigned short*)(base + 97 * MB + 196608); // 24 KB
  float*          bias192= (float*)(base + 97 * MB + 229376);          // 768 B
  float*          biasQG = (float*)(base + 97 * MB + 230400);          // 1 KB
  float*          b21    = (float*)(base + 97 * MB + 231424);          // 256 B
  unsigned short* wbf    = (unsigned short*)(base + 97 * MB + 262144); // 208 KB

  setup_k<<<598, 256, 0, stream>>>(
      ga_qkv_w, ga_gp_w, a1_pw, a2_pw, fc_w, m1_w, m2_w,
      ga_qkv_b, ga_gp_b,
      sw_qkv_w, sw_qkv_b, wn_qkv_w, wn_qkv_b,
      sw_rpb, wn_rpb,
      pos_w1, pos_b1, pos_w2, pos_b2, pos_w3, pos_b3,
      wbf, biasQG, wq2bf, bias192, rpbT_sw, rpbT_wn, ptab);
  wfold_k<<<16, 256, 0, stream>>>(a1_pw, a1_pb, a2_pw, a2_pb, wbf + 20480, b21);
  pbT_k<<<1024, 256, 0, stream>>>(ptab, pbTh);

  tin_k<<<dim3(256, 1, 4), 256, 0, stream>>>(x, xTb);

  // grid branch: one merged qkv+gp GEMM (256 out-ch, NF=8), grid-shuffled
  gemm_k<8, 1, 0, 1><<<dim3(512, 2, 1), 256, 0, stream>>>(
      xTb, 128, 0, wbf, biasQG, nullptr, nullptr, nullptr, nullptr, qgT, 256, 0);

  // fused attn1+attn2 -> t2
  gattn2_k<<<dim3(256, 4), 512, 0, stream>>>(qgT, pbTh, t2T);

  // folded a2 (A2@A1) + unshuffle -> yT[64:128]
  gemm_k<4, 1, 0, 2><<<dim3(512, 1, 1), 256, 0, stream>>>(
      t2T, 64, 0, wbf + 20480, b21, nullptr, nullptr, nullptr, nullptr, yT, 128, 64);

  // window branches: qkv GEMM (window-ordered) + MFMA attention
  gemm_k<6, 1, 0, 3><<<dim3(512, 2, 1), 256, 0, stream>>>(
      xTb, 128, 64, wq2bf, bias192, nullptr, nullptr, nullptr, nullptr, qkv2, 96, 0);
  swat_k<<<dim3(256, 2), 256, 0, stream>>>(
      qkv2, rpbT_sw, rpbT_wn, sw_pw, sw_pb, wn_pw, wn_pb, yT);

  // fc + cLN + residual(x bf16) -> x2T
  gemm_k<8, 2, 2, 0><<<dim3(512, 1, 1), 256, 0, stream>>>(
      yT, 128, 0, wbf + 24576, fc_b, ln_g, ln_b, xTb, nullptr, x2T, 128, 0);

  // MLP: m1 (gelu) -> hT ; m2 + cLN + x2 + shortcut -> out (fp32 NCHW)
  gemm_k<8, 2, 1, 0><<<dim3(512, 2, 1), 256, 0, stream>>>(
      x2T, 128, 0, wbf + 40960, m1_b, nullptr, nullptr, nullptr, nullptr, hT, 256, 0);
  gemm_k<8, 4, 3, 0><<<dim3(512, 1, 1), 256, 0, stream>>>(
      hT, 256, 0, wbf + 73728, m2_b, n2_g, n2_b, xTb, x2T, out, 128, 0);
}

// Round 24
// 176.059 us; speedup vs baseline: 1.0225x; 1.0009x over previous
//
#include <hip/hip_runtime.h>
#include <hip/hip_bf16.h>
#include <cstdint>

// ---------------------------------------------------------------------------
// GABlock, channel-last bf16-MFMA pipeline.
// R24: R20 + gattn2 processes a HEAD PAIR per block: staging reads become
//      full 64B cache lines (2 adjacent heads x 32B), eliminating the
//      half-line re-fetch (~16-20 MB) without relying on scheduler locality.
//      Inner phase loops are byte-identical to R20, run per head.
// ---------------------------------------------------------------------------

typedef __attribute__((ext_vector_type(8))) short bf8_t;   // 8 bf16 (4 VGPR)
typedef __attribute__((ext_vector_type(4))) float f4_t;    // 4 f32 acc

__device__ __forceinline__ float bf2f(unsigned short u) {
  union { unsigned int i; float f; } x; x.i = ((unsigned int)u) << 16; return x.f;
}
__device__ __forceinline__ unsigned short f2bf(float f) {
  union { float f; unsigned int i; } x; x.f = f;
  unsigned int r = x.i + 0x7FFFu + ((x.i >> 16) & 1u);
  return (unsigned short)(r >> 16);
}
// HW packed f32x2 -> bf16x2 (RNE).
__device__ __forceinline__ unsigned int pk2(float a, float b) {
  unsigned int d;
  asm("v_cvt_pk_bf16_f32 %0, %1, %2" : "=v"(d) : "v"(a), "v"(b));
  return d;
}

#define MB (1048576L)

// ---------------- fused setup: weights->bf16, rpbT, wq2, pos MLP -----------
__global__ void setup_k(
    const float* __restrict__ w0, const float* __restrict__ w1,
    const float* __restrict__ w2, const float* __restrict__ w3,
    const float* __restrict__ w4, const float* __restrict__ w5,
    const float* __restrict__ w6,
    const float* __restrict__ qkv_b, const float* __restrict__ gp_b,
    const float* __restrict__ sw_w, const float* __restrict__ sw_b,
    const float* __restrict__ wn_w, const float* __restrict__ wn_b,
    const float* __restrict__ sw_rpb, const float* __restrict__ wn_rpb,
    const float* __restrict__ pw1, const float* __restrict__ pb1,
    const float* __restrict__ pw2, const float* __restrict__ pb2,
    const float* __restrict__ pw3, const float* __restrict__ pb3,
    unsigned short* __restrict__ wbf, float* __restrict__ biasQG,
    unsigned short* __restrict__ wq2, float* __restrict__ b192,
    float* __restrict__ rpbT_sw, float* __restrict__ rpbT_wn,
    float* __restrict__ ptab) {
  const float QS = 0.35355339059327373f;
  int t = blockIdx.x * 256 + threadIdx.x;
  if (t < 106496) {
    const float* src; int off; float sc = 1.0f;
    if (t < 12288)      { src = w0; off = 0; }
    else if (t < 16384) { src = w1; off = 12288; sc = 0.25f; }
    else if (t < 20480) { src = w2; off = 16384; }
    else if (t < 24576) { src = w3; off = 20480; }
    else if (t < 40960) { src = w4; off = 24576; }
    else if (t < 73728) { src = w5; off = 40960; }
    else                { src = w6; off = 73728; }
    wbf[t] = f2bf(src[t - off] * sc);
  } else if (t < 106752) {
    int i = t - 106496;
    biasQG[i] = i < 192 ? qkv_b[i] : gp_b[i - 192] * 0.25f;
  } else if (t < 119040) {
    int i = t - 106752;
    int row = i >> 6, col = i & 63;
    float v = 0.0f;
    if (row < 96) { if (col < 32) v = sw_w[row * 32 + col]; }
    else          { if (col >= 32) v = wn_w[(row - 96) * 32 + col - 32]; }
    if ((row % 96) < 32) v *= QS;
    wq2[i] = f2bf(v);
  } else if (t < 119232) {
    int i = t - 119040;
    float v = i < 96 ? sw_b[i] : wn_b[i - 96];
    if ((i % 96) < 32) v *= QS;
    b192[i] = v;
  } else if (t < 152000) {
    int i = t - 119232;
    const float* rpb = i < 16384 ? sw_rpb : wn_rpb;
    float* dst = i < 16384 ? rpbT_sw : rpbT_wn;
    int j = i & 16383;
    int h = j >> 12, r = j & 4095, m = r >> 6, n = r & 63;
    int idx = ((n >> 3) - (m >> 3) + 7) * 15 + ((n & 7) - (m & 7) + 7);
    dst[j] = rpb[idx * 4 + h];
  } else if (t < 152961) {
    int j = t - 152000;
    float chv = (float)(j / 31) - 15.0f;
    float cwv = (float)(j % 31) - 15.0f;
    float t1[16], t2[16];
#pragma unroll
    for (int i = 0; i < 16; ++i) {
      float s = fmaf(pw1[i * 2], chv, fmaf(pw1[i * 2 + 1], cwv, pb1[i]));
      t1[i] = fmaxf(s, 0.0f);
    }
#pragma unroll
    for (int i = 0; i < 16; ++i) {
      float s = pb2[i];
#pragma unroll
      for (int k = 0; k < 16; ++k) s = fmaf(pw2[i * 16 + k], t1[k], s);
      t2[i] = fmaxf(s, 0.0f);
    }
#pragma unroll
    for (int hh = 0; hh < 4; ++hh) {
      float s = pb3[hh];
#pragma unroll
      for (int k = 0; k < 16; ++k) s = fmaf(pw3[hh * 16 + k], t2[k], s);
      ptab[j * 4 + hh] = s;
    }
  }
}

// A21 = A2 @ A1 (64x64, fp32 accum -> bf16 into wbf a2 slot); b21 = A2@a1_b + a2_b
__global__ void wfold_k(const float* __restrict__ a1w, const float* __restrict__ a1b,
                        const float* __restrict__ a2w, const float* __restrict__ a2b,
                        unsigned short* __restrict__ w21, float* __restrict__ b21) {
  int t = blockIdx.x * 256 + threadIdx.x;   // 4096
  int co = t >> 6, ci = t & 63;
  float s = 0.0f;
#pragma unroll 8
  for (int k = 0; k < 64; ++k) s = fmaf(a2w[co * 64 + k], a1w[k * 64 + ci], s);
  w21[t] = f2bf(s);
  if (t < 64) {
    float b = a2b[t];
#pragma unroll 8
    for (int k = 0; k < 64; ++k) b = fmaf(a2w[t * 64 + k], a1b[k], b);
    b21[t] = b;
  }
}

// pbTh[h][m][q] bf16
__global__ void pbT_k(const float* __restrict__ table, unsigned short* __restrict__ pbTh) {
  int t = blockIdx.x * 256 + threadIdx.x;   // 262144
  int hh = t >> 16;
  int r = t & 65535;
  int m = r >> 8;
  int q = r & 255;
  int idx = ((q >> 4) - (m >> 4) + 15) * 31 + ((q & 15) - (m & 15) + 15);
  pbTh[t] = f2bf(table[idx * 4 + hh]);
}

// ---------------- NCHW fp32 -> channel-last bf16 ---------------------------
__global__ __launch_bounds__(256) void tin_k(const float* __restrict__ x,
                                             unsigned short* __restrict__ xTb) {
  __shared__ float tile[64][132];
  const int b = blockIdx.z, px0 = blockIdx.x * 64, tid = threadIdx.x;
#pragma unroll
  for (int i = 0; i < 8; ++i) {
    int e = i * 256 + tid;
    int c = e >> 4, p4 = (e & 15) * 4;
    float4 v = *(const float4*)(x + (((size_t)(b * 128 + c)) << 14) + px0 + p4);
    tile[p4][c] = v.x; tile[p4 + 1][c] = v.y; tile[p4 + 2][c] = v.z; tile[p4 + 3][c] = v.w;
  }
  __syncthreads();
#pragma unroll
  for (int i = 0; i < 8; ++i) {
    int e = i * 256 + tid;
    int px = e >> 5, c4 = (e & 31) * 4;
    uint2 w = {pk2(tile[px][c4], tile[px][c4 + 1]), pk2(tile[px][c4 + 2], tile[px][c4 + 3])};
    *(uint2*)(xTb + ((size_t)(b * 16384 + px0 + px)) * 128 + c4) = w;
  }
}

// ---------------- generic bf16-MFMA GEMM -----------------------------------
// EPI: 0 plain->bf16, 1 gelu->bf16, 2 cLN+res(bf16)->bf16,
//      3 cLN+res(bf16)+res2(bf16)->f32 NCHW full-line stores
template <int NF, int KC, int EPI, int OSHUF>
__global__ __launch_bounds__(256) void gemm_k(
    const unsigned short* __restrict__ A, int a_rs, int a_c0,
    const unsigned short* __restrict__ W, const float* __restrict__ bias,
    const float* __restrict__ g, const float* __restrict__ bb,
    const unsigned short* __restrict__ resf, const unsigned short* __restrict__ resb,
    void* __restrict__ out, int o_rs, int o_c0) {
  __shared__ __align__(16) char Asw[128 * 128];
  __shared__ __align__(16) char Bsw[NF * 16 * 128];
  const int tid = threadIdx.x;
  const int lane = tid & 63, wv = tid >> 6, wpx = wv * 32;
  const int lr = lane & 15, lg = lane >> 4;
  const int px0 = blockIdx.x * 128;
  const int co0 = blockIdx.y * (NF * 16);

  f4_t acc[2][NF];
#pragma unroll
  for (int mf = 0; mf < 2; ++mf)
#pragma unroll
    for (int nf = 0; nf < NF; ++nf) acc[mf][nf] = (f4_t){0.f, 0.f, 0.f, 0.f};

  for (int kc = 0; kc < KC; ++kc) {
    const int k0 = kc * 64;
    if (kc) __syncthreads();
#pragma unroll
    for (int i = 0; i < 4; ++i) {
      int e = i * 256 + tid;
      int row = e >> 3, q8 = e & 7;
      const unsigned short* src = A + (size_t)(px0 + row) * a_rs + a_c0 + k0 + q8 * 8;
      *(uint4*)(Asw + row * 128 + ((q8 ^ (row & 7)) << 4)) = *(const uint4*)src;
    }
#pragma unroll
    for (int i = 0; i < NF / 2; ++i) {
      int e = i * 256 + tid;
      int row = e >> 3, q8 = e & 7;
      const unsigned short* src = W + (size_t)(co0 + row) * (KC * 64) + k0 + q8 * 8;
      *(uint4*)(Bsw + row * 128 + ((q8 ^ (row & 7)) << 4)) = *(const uint4*)src;
    }
    __syncthreads();
#pragma unroll
    for (int ks = 0; ks < 2; ++ks) {
      const int xk = (((ks * 4) + lg) ^ (lane & 7)) << 4;
      bf8_t av[2], bv[NF];
#pragma unroll
      for (int mf = 0; mf < 2; ++mf)
        av[mf] = *(const bf8_t*)(Asw + (wpx + mf * 16 + lr) * 128 + xk);
#pragma unroll
      for (int nf = 0; nf < NF; ++nf)
        bv[nf] = *(const bf8_t*)(Bsw + (nf * 16 + lr) * 128 + xk);
#pragma unroll
      for (int mf = 0; mf < 2; ++mf)
#pragma unroll
        for (int nf = 0; nf < NF; ++nf)
          acc[mf][nf] = __builtin_amdgcn_mfma_f32_16x16x32_bf16(av[mf], bv[nf], acc[mf][nf], 0, 0, 0);
    }
  }

  float bco[NF];
#pragma unroll
  for (int nf = 0; nf < NF; ++nf) bco[nf] = bias[co0 + nf * 16 + lr];

  if constexpr (EPI >= 2) {
    float gv[NF], bbv[NF];
#pragma unroll
    for (int nf = 0; nf < NF; ++nf) { gv[nf] = g[nf * 16 + lr]; bbv[nf] = bb[nf * 16 + lr]; }
#pragma unroll
    for (int mf = 0; mf < 2; ++mf)
#pragma unroll
      for (int nf = 0; nf < NF; ++nf)
#pragma unroll
        for (int r = 0; r < 4; ++r) acc[mf][nf][r] += bco[nf];
#pragma unroll
    for (int mf = 0; mf < 2; ++mf) {
      float mus[4], rss[4];
#pragma unroll
      for (int r = 0; r < 4; ++r) {
        float s = 0.f, q = 0.f;
#pragma unroll
        for (int nf = 0; nf < NF; ++nf) {
          float v = acc[mf][nf][r];
          s += v; q += v * v;
        }
#pragma unroll
        for (int msk = 1; msk < 16; msk <<= 1) {
          s += __shfl_xor(s, msk);
          q += __shfl_xor(q, msk);
        }
        float mu = s * (1.0f / 128.0f);
        float var = q * (1.0f / 128.0f) - mu * mu;
        mus[r] = mu;
        rss[r] = rsqrtf(var + 1e-5f);
      }
      if constexpr (EPI == 2) {
#pragma unroll
        for (int r = 0; r < 4; ++r) {
          int px_e = px0 + wpx + mf * 16 + lg * 4 + r;
          const unsigned short* xr = resf + (size_t)px_e * 128 + lr;
          unsigned short* op = (unsigned short*)out + (size_t)px_e * o_rs + lr;
#pragma unroll
          for (int nf = 0; nf < NF; ++nf) {
            float v = (acc[mf][nf][r] - mus[r]) * rss[r] * gv[nf] + bbv[nf] + bf2f(xr[nf * 16]);
            op[nf * 16] = f2bf(v);
          }
        }
      } else {  // EPI == 3: fp32 NCHW, one float4 (4 px) per channel per thread
        int pxb = px0 + wpx + mf * 16 + lg * 4;
        int b_ = pxb >> 14, p_ = pxb & 16383;
#pragma unroll
        for (int nf = 0; nf < NF; ++nf) {
          int ch = lr + nf * 16;
          float vr[4];
#pragma unroll
          for (int r = 0; r < 4; ++r) {
            float xv  = bf2f(resf[(size_t)(pxb + r) * 128 + ch]);
            float x2v = bf2f(resb[(size_t)(pxb + r) * 128 + ch]);
            vr[r] = (acc[mf][nf][r] - mus[r]) * rss[r] * gv[nf] + bbv[nf] + xv + x2v;
          }
          float4 v4 = {vr[0], vr[1], vr[2], vr[3]};
          *(float4*)((float*)out + (((size_t)(b_ * 128 + ch)) << 14) + p_) = v4;
        }
      }
    }
  } else {
#pragma unroll
    for (int mf = 0; mf < 2; ++mf) {
#pragma unroll
      for (int r = 0; r < 4; ++r) {
        int px_e = px0 + wpx + mf * 16 + lg * 4 + r;
        size_t orow;
        int cadj = co0;
        if constexpr (OSHUF == 0) {
          orow = (size_t)px_e;
        } else if constexpr (OSHUF == 1) {
          int b = px_e >> 14, p = px_e & 16383, hh = p >> 7, w_ = p & 127;
          orow = (size_t)(b * 64 + (hh & 7) * 8 + (w_ & 7)) * 256 + ((hh >> 3) * 16 + (w_ >> 3));
        } else if constexpr (OSHUF == 2) {
          int gbb = px_e >> 8, n = px_e & 255;
          int b = gbb >> 6, ih = (gbb >> 3) & 7, iw = gbb & 7;
          orow = (size_t)b * 16384 + ((n >> 4) * 8 + ih) * 128 + (n & 15) * 8 + iw;
        } else {  // window-order: br0 = sw(shift 4), br1 = wn(shift 0)
          int brx = (co0 >= 96);
          int b = px_e >> 14, p = px_e & 16383, hh = p >> 7, w_ = p & 127;
          int sh = brx ? 0 : 4;
          int h2 = (hh - sh) & 127, w2_ = (w_ - sh) & 127;
          orow = (size_t)brx * 65536 + (size_t)b * 16384 +
                 (size_t)(((h2 >> 3) * 16 + (w2_ >> 3)) * 64 + (h2 & 7) * 8 + (w2_ & 7));
          cadj = co0 - brx * 96;
        }
        unsigned short* op = (unsigned short*)out + orow * o_rs + o_c0 + cadj + lr;
#pragma unroll
        for (int nf = 0; nf < NF; ++nf) {
          float v = acc[mf][nf][r] + bco[nf];
          if constexpr (EPI == 1) v = 0.5f * v * (1.0f + erff(v * 0.7071067811865475f));
          op[nf * 16] = f2bf(v);
        }
      }
    }
  }
}

// ---------------- fused double grid attention, head-pair blocks ------------
// Block = (gb, hp), 512 threads; processes heads h = 2*hp and 2*hp+1.
// Staging reads 64B full lines (2 heads x 32B adjacent). Per head, the
// proven R20 phase-1 / phase-2 loops run unchanged.
__global__ __launch_bounds__(512, 4) void gattn2_k(
    const unsigned short* __restrict__ qgT,
    const unsigned short* __restrict__ pbTh, unsigned short* __restrict__ outb) {
  __shared__ __align__(16) unsigned short K_lds[2][256 * 16];  // 16 KB
  __shared__ __align__(16) unsigned short G_lds[2][256 * 16];  // 16 KB
  __shared__ __align__(16) unsigned short Vt[2][16 * 256];     // 16 KB
  __shared__ __align__(16) unsigned short Vt2[2][16 * 256];    // 16 KB (O1)
  __shared__ __align__(16) unsigned short P_lds[8 * 32 * 32];  // 16 KB
  const int gb = blockIdx.x, hp = blockIdx.y, tid = threadIdx.x;
  const int lane = tid & 63, wv = tid >> 6;        // wv in [0,8)
  const int lr = lane & 15, lg = lane >> 4;
  const int q0 = wv * 32;
  const f4_t z4 = {0.f, 0.f, 0.f, 0.f};
  const bf8_t bz = {0, 0, 0, 0, 0, 0, 0, 0};
  unsigned short* Pw = &P_lds[wv * 32 * 32];

  // ---- stage K+G rows (threads 0-255) and V^T (threads 256-511), 2 heads --
  if (tid < 256) {
    const unsigned short* kp = qgT + (size_t)(gb * 256 + tid) * 256 + 64 + hp * 32;
    *(uint4*)&K_lds[0][tid * 16]     = *(const uint4*)kp;
    *(uint4*)&K_lds[0][tid * 16 + 8] = *(const uint4*)(kp + 8);
    *(uint4*)&K_lds[1][tid * 16]     = *(const uint4*)(kp + 16);
    *(uint4*)&K_lds[1][tid * 16 + 8] = *(const uint4*)(kp + 24);
    const unsigned short* gp = qgT + (size_t)(gb * 256 + tid) * 256 + 192 + hp * 32;
    *(uint4*)&G_lds[0][tid * 16]     = *(const uint4*)gp;
    *(uint4*)&G_lds[0][tid * 16 + 8] = *(const uint4*)(gp + 8);
    *(uint4*)&G_lds[1][tid * 16]     = *(const uint4*)(gp + 16);
    *(uint4*)&G_lds[1][tid * 16 + 8] = *(const uint4*)(gp + 24);
  } else {
    int m = tid - 256;
    const unsigned short* vp = qgT + (size_t)(gb * 256 + m) * 256 + 128 + hp * 32;
    int chb = m >> 3, wi = m & 7;
#pragma unroll
    for (int hh = 0; hh < 2; ++hh) {
      uint4 va = *(const uint4*)(vp + hh * 16);
      uint4 vb = *(const uint4*)(vp + hh * 16 + 8);
      unsigned int w8[8] = {va.x, va.y, va.z, va.w, vb.x, vb.y, vb.z, vb.w};
#pragma unroll
      for (int w = 0; w < 8; ++w) {
        int d0 = 2 * w, d1 = 2 * w + 1;
        Vt[hh][d0 * 256 + ((chb ^ (d0 & 7)) << 3) + wi] = (unsigned short)(w8[w] & 0xffff);
        Vt[hh][d1 * 256 + ((chb ^ (d1 & 7)) << 3) + wi] = (unsigned short)(w8[w] >> 16);
      }
    }
  }
  __syncthreads();

  // ================= phase 1 (both heads): O1 = softmax(G K^T + B) V =======
#pragma unroll 1
  for (int hh = 0; hh < 2; ++hh) {
    const unsigned short* bpm_base = pbTh + ((size_t)((hp * 2 + hh) * 256) << 8);
    bf8_t bq[2];
#pragma unroll
    for (int qt = 0; qt < 2; ++qt) {
      bq[qt] = bz;
      if (lg < 2)
        bq[qt] = *(const bf8_t*)&G_lds[hh][(q0 + qt * 16 + lr) * 16 + lg * 8];
    }
    f4_t oacc[2];
    float lrun[2];
#pragma unroll
    for (int qt = 0; qt < 2; ++qt) { oacc[qt] = z4; lrun[qt] = 0.0f; }

    for (int m0 = 0; m0 < 256; m0 += 32) {
      bf8_t ak0 = bz, ak1 = bz;
      if (lg < 2) {
        ak0 = *(const bf8_t*)&K_lds[hh][(m0 + lr) * 16 + lg * 8];
        ak1 = *(const bf8_t*)&K_lds[hh][(m0 + 16 + lr) * 16 + lg * 8];
      }
      bf8_t av = *(const bf8_t*)&Vt[hh][lr * 256 + ((((m0 >> 3) + lg) ^ (lr & 7)) << 3)];

#pragma unroll
      for (int qt = 0; qt < 2; ++qt) {
        const unsigned short* bpm = bpm_base + ((size_t)(m0 + lg * 4) << 8) + q0 + qt * 16 + lr;
        f4_t c0v = {bf2f(bpm[0]), bf2f(bpm[256]), bf2f(bpm[512]), bf2f(bpm[768])};
        f4_t c1v = {bf2f(bpm[4096]), bf2f(bpm[4352]), bf2f(bpm[4608]), bf2f(bpm[4864])};
        f4_t st0 = __builtin_amdgcn_mfma_f32_16x16x32_bf16(ak0, bq[qt], c0v, 0, 0, 0);
        f4_t st1 = __builtin_amdgcn_mfma_f32_16x16x32_bf16(ak1, bq[qt], c1v, 0, 0, 0);
        float p0[4], p1[4], ls = 0.0f;
#pragma unroll
        for (int r = 0; r < 4; ++r) {
          p0[r] = __expf(st0[r]);
          p1[r] = __expf(st1[r]);
          ls += p0[r] + p1[r];
        }
        ls += __shfl_xor(ls, 16);
        ls += __shfl_xor(ls, 32);
        lrun[qt] += ls;
        int row = qt * 16 + lr;
        int rw3 = row & 3;
        uint2 w0 = {pk2(p0[0], p0[1]), pk2(p0[2], p0[3])};
        uint2 w1 = {pk2(p1[0], p1[1]), pk2(p1[2], p1[3])};
        *(uint2*)&Pw[row * 32 + ((((lg >> 1)) ^ rw3) << 3) + (lg & 1) * 4]     = w0;
        *(uint2*)&Pw[row * 32 + (((2 + (lg >> 1)) ^ rw3) << 3) + (lg & 1) * 4] = w1;
      }
#pragma unroll
      for (int qt = 0; qt < 2; ++qt) {
        int row = qt * 16 + lr;
        bf8_t bp = *(const bf8_t*)&Pw[row * 32 + ((lg ^ (row & 3)) << 3)];
        oacc[qt] = __builtin_amdgcn_mfma_f32_16x16x32_bf16(av, bp, oacc[qt], 0, 0, 0);
      }
    }
    // O1 -> Vt2 (swizzled [d][m]): lane holds O^T[d = lg*4+r][m = q0+qt*16+lr]
#pragma unroll
    for (int qt = 0; qt < 2; ++qt) {
      float inv = 1.0f / lrun[qt];
      int m = q0 + qt * 16 + lr;
      int chb = m >> 3, wi = m & 7;
      unsigned int pA = pk2(oacc[qt][0] * inv, oacc[qt][1] * inv);
      unsigned int pB = pk2(oacc[qt][2] * inv, oacc[qt][3] * inv);
      int d0 = lg * 4;
      Vt2[hh][(d0    ) * 256 + ((chb ^ ((d0    ) & 7)) << 3) + wi] = (unsigned short)(pA & 0xffff);
      Vt2[hh][(d0 + 1) * 256 + ((chb ^ ((d0 + 1) & 7)) << 3) + wi] = (unsigned short)(pA >> 16);
      Vt2[hh][(d0 + 2) * 256 + ((chb ^ ((d0 + 2) & 7)) << 3) + wi] = (unsigned short)(pB & 0xffff);
      Vt2[hh][(d0 + 3) * 256 + ((chb ^ ((d0 + 3) & 7)) << 3) + wi] = (unsigned short)(pB >> 16);
    }
  }
  __syncthreads();

  // ================= phase 2 (both heads): O2 = softmax(q G^T + B) O1 ======
#pragma unroll 1
  for (int hh = 0; hh < 2; ++hh) {
    const int h = hp * 2 + hh;
    const unsigned short* bpm_base = pbTh + ((size_t)(h * 256) << 8);
    bf8_t bq[2];
#pragma unroll
    for (int qt = 0; qt < 2; ++qt) {
      bq[qt] = bz;
      if (lg < 2)
        bq[qt] = *(const bf8_t*)(qgT + (size_t)(gb * 256 + q0 + qt * 16 + lr) * 256 + h * 16 + lg * 8);
    }
    f4_t oacc[2];
    float lrun[2];
#pragma unroll
    for (int qt = 0; qt < 2; ++qt) { oacc[qt] = z4; lrun[qt] = 0.0f; }

    for (int m0 = 0; m0 < 256; m0 += 32) {
      bf8_t ak0 = bz, ak1 = bz;
      if (lg < 2) {
        ak0 = *(const bf8_t*)&G_lds[hh][(m0 + lr) * 16 + lg * 8];
        ak1 = *(const bf8_t*)&G_lds[hh][(m0 + 16 + lr) * 16 + lg * 8];
      }
      bf8_t av = *(const bf8_t*)&Vt2[hh][lr * 256 + ((((m0 >> 3) + lg) ^ (lr & 7)) << 3)];

#pragma unroll
      for (int qt = 0; qt < 2; ++qt) {
        const unsigned short* bpm = bpm_base + ((size_t)(m0 + lg * 4) << 8) + q0 + qt * 16 + lr;
        f4_t c0v = {bf2f(bpm[0]), bf2f(bpm[256]), bf2f(bpm[512]), bf2f(bpm[768])};
        f4_t c1v = {bf2f(bpm[4096]), bf2f(bpm[4352]), bf2f(bpm[4608]), bf2f(bpm[4864])};
        f4_t st0 = __builtin_amdgcn_mfma_f32_16x16x32_bf16(ak0, bq[qt], c0v, 0, 0, 0);
        f4_t st1 = __builtin_amdgcn_mfma_f32_16x16x32_bf16(ak1, bq[qt], c1v, 0, 0, 0);
        float p0[4], p1[4], ls = 0.0f;
#pragma unroll
        for (int r = 0; r < 4; ++r) {
          p0[r] = __expf(st0[r]);
          p1[r] = __expf(st1[r]);
          ls += p0[r] + p1[r];
        }
        ls += __shfl_xor(ls, 16);
        ls += __shfl_xor(ls, 32);
        lrun[qt] += ls;
        int row = qt * 16 + lr;
        int rw3 = row & 3;
        uint2 w0 = {pk2(p0[0], p0[1]), pk2(p0[2], p0[3])};
        uint2 w1 = {pk2(p1[0], p1[1]), pk2(p1[2], p1[3])};
        *(uint2*)&Pw[row * 32 + ((((lg >> 1)) ^ rw3) << 3) + (lg & 1) * 4]     = w0;
        *(uint2*)&Pw[row * 32 + (((2 + (lg >> 1)) ^ rw3) << 3) + (lg & 1) * 4] = w1;
      }
#pragma unroll
      for (int qt = 0; qt < 2; ++qt) {
        int row = qt * 16 + lr;
        bf8_t bp = *(const bf8_t*)&Pw[row * 32 + ((lg ^ (row & 3)) << 3)];
        oacc[qt] = __builtin_amdgcn_mfma_f32_16x16x32_bf16(av, bp, oacc[qt], 0, 0, 0);
      }
    }
#pragma unroll
    for (int qt = 0; qt < 2; ++qt) {
      float inv = 1.0f / lrun[qt];
      uint2 o;
      o.x = pk2(oacc[qt][0] * inv, oacc[qt][1] * inv);
      o.y = pk2(oacc[qt][2] * inv, oacc[qt][3] * inv);
      unsigned short* op = outb + (size_t)(gb * 256 + q0 + qt * 16 + lr) * 64 + h * 16 + lg * 4;
      *(uint2*)op = o;
    }
  }
}

// ---------------- MFMA swin window attention (barrier-free) ----------------
__global__ __launch_bounds__(256) void swat_k(
    const unsigned short* __restrict__ qkv2,
    const float* __restrict__ rpbT_sw, const float* __restrict__ rpbT_wn,
    const float* __restrict__ sw_pw, const float* __restrict__ sw_pb,
    const float* __restrict__ wn_pw, const float* __restrict__ wn_pb,
    unsigned short* __restrict__ yT) {
  __shared__ __align__(16) unsigned short Vt[4 * 8 * 64];
  __shared__ __align__(16) unsigned short Pt[4 * 64 * 64];
  __shared__ __align__(16) unsigned short aoT[4 * 64 * 32];
  const int tid = threadIdx.x, lane = tid & 63, wv = tid >> 6;
  const int lr = lane & 15, lg = lane >> 4;
  const int br = blockIdx.y;
  const int win = blockIdx.x * 4 + wv;
  const int b = win >> 8, wl = win & 255, wh = wl >> 4, ww = wl & 15;
  const float* rpbT = br ? rpbT_wn : rpbT_sw;
  const float* pw   = br ? wn_pw : sw_pw;
  const float* pb   = br ? wn_pb : sw_pb;
  const int shift = br ? 0 : 4;
  const int yc0 = br ? 0 : 32;
  const bool edge = (shift > 0) && (wh == 15 || ww == 15);

  const unsigned short* qw = qkv2 + (size_t)br * 65536 * 96 + (size_t)win * 64 * 96;
  const f4_t z4 = {0.f, 0.f, 0.f, 0.f};
  const bf8_t bz = {0, 0, 0, 0, 0, 0, 0, 0};
  unsigned short* Vw = &Vt[wv * 8 * 64];
  unsigned short* Pw = &Pt[wv * 64 * 64];
  unsigned short* aw_ = &aoT[wv * 64 * 32];

#pragma unroll 1
  for (int h = 0; h < 4; ++h) {
    {
      uint4 v = *(const uint4*)(qw + lane * 96 + 64 + h * 8);
      unsigned int w4[4] = {v.x, v.y, v.z, v.w};
      int chb = lane >> 3, wi = lane & 7;
#pragma unroll
      for (int j = 0; j < 4; ++j) {
        int d0 = 2 * j, d1 = 2 * j + 1;
        Vw[d0 * 64 + ((chb ^ (d0 & 7)) << 3) + wi] = (unsigned short)(w4[j] & 0xffff);
        Vw[d1 * 64 + ((chb ^ (d1 & 7)) << 3) + wi] = (unsigned short)(w4[j] >> 16);
      }
    }
    bf8_t bq[4];
#pragma unroll
    for (int nt = 0; nt < 4; ++nt) {
      bq[nt] = bz;
      if (lg == 0) bq[nt] = *(const bf8_t*)(qw + (nt * 16 + lr) * 96 + h * 8);
    }
    f4_t st[4][4];
#pragma unroll
    for (int mt = 0; mt < 4; ++mt) {
      bf8_t ak = bz;
      if (lg == 0) ak = *(const bf8_t*)(qw + (mt * 16 + lr) * 96 + 32 + h * 8);
#pragma unroll
      for (int nt = 0; nt < 4; ++nt) {
        const float* rp = rpbT + h * 4096 + (mt * 16 + lg * 4) * 64 + nt * 16 + lr;
        f4_t cb = {rp[0], rp[64], rp[128], rp[192]};
        st[mt][nt] = __builtin_amdgcn_mfma_f32_16x16x32_bf16(ak, bq[nt], cb, 0, 0, 0);
      }
    }
#pragma unroll
    for (int nt = 0; nt < 4; ++nt) {
      float sv[16];
#pragma unroll
      for (int mt = 0; mt < 4; ++mt)
#pragma unroll
        for (int r = 0; r < 4; ++r) sv[mt * 4 + r] = st[mt][nt][r];
      if (edge) {
        int n = nt * 16 + lr;
        int regn = ((wh < 15) ? 0 : (((n >> 3) < 4) ? 1 : 2)) * 3 +
                   ((ww < 15) ? 0 : (((n & 7) < 4) ? 1 : 2));
#pragma unroll
        for (int mt = 0; mt < 4; ++mt)
#pragma unroll
          for (int r = 0; r < 4; ++r) {
            int m = mt * 16 + lg * 4 + r;
            int regm = ((wh < 15) ? 0 : (((m >> 3) < 4) ? 1 : 2)) * 3 +
                       ((ww < 15) ? 0 : (((m & 7) < 4) ? 1 : 2));
            if (regm != regn) sv[mt * 4 + r] -= 100.0f;
          }
      }
      float l = 0.0f;
#pragma unroll
      for (int i = 0; i < 16; ++i) {
        sv[i] = __expf(sv[i]);
        l += sv[i];
      }
      l += __shfl_xor(l, 16);
      l += __shfl_xor(l, 32);
      float inv = 1.0f / l;
      int row = nt * 16 + lr, rw7 = lr & 7;
#pragma unroll
      for (int mt = 0; mt < 4; ++mt) {
        uint2 w = {pk2(sv[mt * 4] * inv, sv[mt * 4 + 1] * inv),
                   pk2(sv[mt * 4 + 2] * inv, sv[mt * 4 + 3] * inv)};
        *(uint2*)&Pw[row * 64 + (((2 * mt + (lg >> 1)) ^ rw7) << 3) + (lg & 1) * 4] = w;
      }
    }
    f4_t oa[4] = {z4, z4, z4, z4};
#pragma unroll
    for (int ks = 0; ks < 2; ++ks) {
      bf8_t av = bz;
      if (lr < 8) av = *(const bf8_t*)&Vw[lr * 64 + (((4 * ks + lg) ^ (lr & 7)) << 3)];
#pragma unroll
      for (int nt = 0; nt < 4; ++nt) {
        int row = nt * 16 + lr;
        bf8_t bp = *(const bf8_t*)&Pw[row * 64 + (((4 * ks + lg) ^ (lr & 7)) << 3)];
        oa[nt] = __builtin_amdgcn_mfma_f32_16x16x32_bf16(av, bp, oa[nt], 0, 0, 0);
      }
    }
    if (lg < 2) {
#pragma unroll
      for (int nt = 0; nt < 4; ++nt) {
        uint2 w = {pk2(oa[nt][0], oa[nt][1]), pk2(oa[nt][2], oa[nt][3])};
        int row = nt * 16 + lr;
        *(uint2*)&aw_[row * 32 + ((h ^ (lr & 3)) << 3) + lg * 4] = w;
      }
    }
  }

#pragma unroll
  for (int mt = 0; mt < 2; ++mt) {
    const float* wr = pw + (mt * 16 + lr) * 32 + lg * 8;
    float4 a0 = *(const float4*)wr, a1 = *(const float4*)(wr + 4);
    union { uint4 u; bf8_t v; } aw;
    aw.u.x = pk2(a0.x, a0.y); aw.u.y = pk2(a0.z, a0.w);
    aw.u.z = pk2(a1.x, a1.y); aw.u.w = pk2(a1.z, a1.w);
    float pb0 = pb[mt * 16 + lg * 4], pb1 = pb[mt * 16 + lg * 4 + 1];
    float pb2 = pb[mt * 16 + lg * 4 + 2], pb3 = pb[mt * 16 + lg * 4 + 3];
#pragma unroll
    for (int nt = 0; nt < 4; ++nt) {
      int row = nt * 16 + lr;
      bf8_t bo = *(const bf8_t*)&aw_[row * 32 + ((lg ^ (lr & 3)) << 3)];
      f4_t po = __builtin_amdgcn_mfma_f32_16x16x32_bf16(aw.v, bo, z4, 0, 0, 0);
      int n = nt * 16 + lr;
      int hdst = (wh * 8 + (n >> 3) + shift) & 127;
      int wdst = (ww * 8 + (n & 7) + shift) & 127;
      uint2 w = {pk2(po[0] + pb0, po[1] + pb1), pk2(po[2] + pb2, po[3] + pb3)};
      *(uint2*)(yT + ((size_t)(b * 16384 + hdst * 128 + wdst)) * 128 + yc0 + mt * 16 + lg * 4) = w;
    }
  }
}

// ---------------------------------------------------------------------------
extern "C" void kernel_launch(void* const* d_in, const int* in_sizes, int n_in,
                              void* d_out, int out_size, void* d_ws, size_t ws_size,
                              hipStream_t stream) {
  (void)in_sizes; (void)n_in; (void)out_size; (void)ws_size;
  const float* x        = (const float*)d_in[0];
  const float* ln_g     = (const float*)d_in[1];
  const float* ln_b     = (const float*)d_in[2];
  const float* ga_qkv_w = (const float*)d_in[3];
  const float* ga_qkv_b = (const float*)d_in[4];
  const float* ga_gp_w  = (const float*)d_in[5];
  const float* ga_gp_b  = (const float*)d_in[6];
  const float* pos_w1   = (const float*)d_in[7];
  const float* pos_b1   = (const float*)d_in[8];
  const float* pos_w2   = (const float*)d_in[9];
  const float* pos_b2   = (const float*)d_in[10];
  const float* pos_w3   = (const float*)d_in[11];
  const float* pos_b3   = (const float*)d_in[12];
  const float* a1_pw    = (const float*)d_in[13];
  const float* a1_pb    = (const float*)d_in[14];
  const float* a2_pw    = (const float*)d_in[15];
  const float* a2_pb    = (const float*)d_in[16];
  const float* sw_qkv_w = (const float*)d_in[17];
  const float* sw_qkv_b = (const float*)d_in[18];
  const float* sw_rpb   = (const float*)d_in[19];
  const float* sw_pw    = (const float*)d_in[20];
  const float* sw_pb    = (const float*)d_in[21];
  const float* wn_qkv_w = (const float*)d_in[22];
  const float* wn_qkv_b = (const float*)d_in[23];
  const float* wn_rpb   = (const float*)d_in[24];
  const float* wn_pw    = (const float*)d_in[25];
  const float* wn_pb    = (const float*)d_in[26];
  const float* fc_w     = (const float*)d_in[27];
  const float* fc_b     = (const float*)d_in[28];
  const float* n2_g     = (const float*)d_in[29];
  const float* n2_b     = (const float*)d_in[30];
  const float* m1_w     = (const float*)d_in[31];
  const float* m1_b     = (const float*)d_in[32];
  const float* m2_w     = (const float*)d_in[33];
  const float* m2_b     = (const float*)d_in[34];
  float* out = (float*)d_out;
  char* base = (char*)d_ws;

  unsigned short* xTb    = (unsigned short*)(base);           // 16 MB
  unsigned short* qgT    = (unsigned short*)(base + 16 * MB); // 32 MB [px][256: q|k|v|g]
  unsigned short* t2T    = (unsigned short*)(base + 48 * MB); //  8 MB
  unsigned short* yT     = (unsigned short*)(base + 64 * MB); // 16 MB
  unsigned short* x2T    = (unsigned short*)(base + 80 * MB); // 16 MB
  unsigned short* qkv2   = (unsigned short*)(base + 16 * MB); // 24 MB alias (after gattn)
  unsigned short* hT     = (unsigned short*)(base + 16 * MB); // 32 MB alias (after swat)
  unsigned short* pbTh   = (unsigned short*)(base + 96 * MB); // 512 KB bf16 [h][m][q]
  float*          ptab   = (float*)(base + 97 * MB);          // 16 KB
  float*          rpbT_sw= (float*)(base + 97 * MB + 65536);  // 64 KB f32
  float*          rpbT_wn= (float*)(base + 97 * MB + 131072); // 64 KB f32
  unsigned short* wq2bf  = (unsigned short*)(base + 97 * MB + 196608); // 24 KB
  float*          bias192= (float*)(base + 97 * MB + 229376);          // 768 B
  float*          biasQG = (float*)(base + 97 * MB + 230400);          // 1 KB
  float*          b21    = (float*)(base + 97 * MB + 231424);          // 256 B
  unsigned short* wbf    = (unsigned short*)(base + 97 * MB + 262144); // 208 KB

  setup_k<<<598, 256, 0, stream>>>(
      ga_qkv_w, ga_gp_w, a1_pw, a2_pw, fc_w, m1_w, m2_w,
      ga_qkv_b, ga_gp_b,
      sw_qkv_w, sw_qkv_b, wn_qkv_w, wn_qkv_b,
      sw_rpb, wn_rpb,
      pos_w1, pos_b1, pos_w2, pos_b2, pos_w3, pos_b3,
      wbf, biasQG, wq2bf, bias192, rpbT_sw, rpbT_wn, ptab);
  wfold_k<<<16, 256, 0, stream>>>(a1_pw, a1_pb, a2_pw, a2_pb, wbf + 20480, b21);
  pbT_k<<<1024, 256, 0, stream>>>(ptab, pbTh);

  tin_k<<<dim3(256, 1, 4), 256, 0, stream>>>(x, xTb);

  // grid branch: one merged qkv+gp GEMM (256 out-ch, NF=8), grid-shuffled
  gemm_k<8, 1, 0, 1><<<dim3(512, 2, 1), 256, 0, stream>>>(
      xTb, 128, 0, wbf, biasQG, nullptr, nullptr, nullptr, nullptr, qgT, 256, 0);

  // fused attn1+attn2 -> t2  (one block per (gb, head-pair))
  gattn2_k<<<dim3(256, 2), 512, 0, stream>>>(qgT, pbTh, t2T);

  // folded a2 (A2@A1) + unshuffle -> yT[64:128]
  gemm_k<4, 1, 0, 2><<<dim3(512, 1, 1), 256, 0, stream>>>(
      t2T, 64, 0, wbf + 20480, b21, nullptr, nullptr, nullptr, nullptr, yT, 128, 64);

  // window branches: qkv GEMM (window-ordered) + MFMA attention
  gemm_k<6, 1, 0, 3><<<dim3(512, 2, 1), 256, 0, stream>>>(
      xTb, 128, 64, wq2bf, bias192, nullptr, nullptr, nullptr, nullptr, qkv2, 96, 0);
  swat_k<<<dim3(256, 2), 256, 0, stream>>>(
      qkv2, rpbT_sw, rpbT_wn, sw_pw, sw_pb, wn_pw, wn_pb, yT);

  // fc + cLN + residual(x bf16) -> x2T
  gemm_k<8, 2, 2, 0><<<dim3(512, 1, 1), 256, 0, stream>>>(
      yT, 128, 0, wbf + 24576, fc_b, ln_g, ln_b, xTb, nullptr, x2T, 128, 0);

  // MLP: m1 (gelu) -> hT ; m2 + cLN + x2 + shortcut -> out (fp32 NCHW)
  gemm_k<8, 2, 1, 0><<<dim3(512, 2, 1), 256, 0, stream>>>(
      x2T, 128, 0, wbf + 40960, m1_b, nullptr, nullptr, nullptr, nullptr, hT, 256, 0);
  gemm_k<8, 4, 3, 0><<<dim3(512, 1, 1), 256, 0, stream>>>(
      hT, 256, 0, wbf + 73728, m2_b, n2_g, n2_b, xTb, x2T, out, 128, 0);
}